// Round 1
// baseline (2718.544 us; speedup 1.0000x reference)
//
#include <hip/hip_runtime.h>
#include <math.h>

#define S_LEN 2048
#define DMODEL 2048
#define NHQ 16
#define NHK 4
#define HDIM 128
#define PDIM 8192
#define VOCAB 32000
#define NQKV 3072          // D + 2*HK*HD
#define EPSI 1e-5f

typedef unsigned short u16;
typedef unsigned int u32;
typedef __bf16 bf16x8 __attribute__((ext_vector_type(8)));
typedef float f32x4 __attribute__((ext_vector_type(4)));

__device__ __forceinline__ u16 f2bf(float f){
  u32 u = __builtin_bit_cast(u32, f);
  u += 0x7fffu + ((u >> 16) & 1u);   // RNE
  return (u16)(u >> 16);
}
__device__ __forceinline__ float bf2f(u16 h){
  u32 u = ((u32)h) << 16;
  return __builtin_bit_cast(float, u);
}
__device__ __forceinline__ bf16x8 ld8(const u16* p){
  return __builtin_bit_cast(bf16x8, *(const uint4*)p);
}
__device__ __forceinline__ f32x4 mfma16(bf16x8 a, bf16x8 b, f32x4 c){
  return __builtin_amdgcn_mfma_f32_16x16x32_bf16(a, b, c, 0, 0, 0);
}

#define GLOAD_LDS16(gp, lp) __builtin_amdgcn_global_load_lds( \
    (__attribute__((address_space(1))) void*)(gp), \
    (__attribute__((address_space(3))) void*)(lp), 16, 0, 0)

// -------------------- embed gather --------------------
__global__ void k_embed(const int* __restrict__ tok, const float* __restrict__ emb,
                        float* __restrict__ x){
  const int s = blockIdx.x, t = threadIdx.x;
  const long r = tok[s];
  const float4* src = (const float4*)(emb + r * DMODEL);
  float4* dst = (float4*)(x + (long)s * DMODEL);
  dst[t] = src[t];
  dst[t + 256] = src[t + 256];
}

// -------------------- RMSNorm: fp32 in -> bf16 out --------------------
__global__ void k_rmsnorm(const float* __restrict__ x, const float* __restrict__ w,
                          u16* __restrict__ out){
  const int s = blockIdx.x, t = threadIdx.x;
  const float4* xr = (const float4*)(x + (long)s * DMODEL);
  const float4 a = xr[t], b = xr[t + 256];
  float ss = a.x*a.x + a.y*a.y + a.z*a.z + a.w*a.w
           + b.x*b.x + b.y*b.y + b.z*b.z + b.w*b.w;
  #pragma unroll
  for (int off = 32; off > 0; off >>= 1) ss += __shfl_down(ss, off, 64);
  __shared__ float part[4];
  if ((t & 63) == 0) part[t >> 6] = ss;
  __syncthreads();
  const float r = rsqrtf((part[0] + part[1] + part[2] + part[3]) * (1.f / 2048.f) + EPSI);
  const float4* wr = (const float4*)w;
  const float4 wa = wr[t], wb = wr[t + 256];
  uint2 ua, ub;
  ua.x = (u32)f2bf(a.x*r*wa.x) | ((u32)f2bf(a.y*r*wa.y) << 16);
  ua.y = (u32)f2bf(a.z*r*wa.z) | ((u32)f2bf(a.w*r*wa.w) << 16);
  ub.x = (u32)f2bf(b.x*r*wb.x) | ((u32)f2bf(b.y*r*wb.y) << 16);
  ub.y = (u32)f2bf(b.z*r*wb.z) | ((u32)f2bf(b.w*r*wb.w) << 16);
  *(uint2*)(out + (long)s * DMODEL + 4 * t) = ua;
  *(uint2*)(out + (long)s * DMODEL + 1024 + 4 * t) = ub;
}

// -------------------- GEMM: C[M,N] = A_bf16[M,K] @ B_f32[K,N] --------------------
// 128x128 tile, BK=32, 4 waves (each 64x64 = 4x4 frags of 16x16x32 MFMA).
// A staged linear via global_load_lds (width 16); B reg-staged, converted to bf16,
// stored transposed [col][k] with stride 40 (pad to break bank conflicts).
template<int OUT_BF16, int RES>
__global__ __launch_bounds__(256) void k_gemm(const u16* __restrict__ A, const float* __restrict__ B,
                                              void* C, const float* Rs,
                                              int M, int N, int K){
  const int bn = blockIdx.x, bm = blockIdx.y;
  const int t = threadIdx.x;
  const int w = t >> 6, lane = t & 63, l15 = lane & 15, g = lane >> 4;
  const int wr = w >> 1, wc = w & 1;
  __shared__ u16 As[128 * 32];    // linear [row][k]
  __shared__ u16 Bs[128 * 40];    // [col][k] (transposed, padded)
  f32x4 acc[4][4] = {};
  const long arow = (long)bm * 128;
  const int bk0 = (t >> 5) << 2;        // B-stage k0 (0..28)
  const int bc0 = (t & 31) << 2;        // B-stage col0 (0..124)
  for (int kt = 0; kt < K; kt += 32){
    __syncthreads();
    // ---- stage A (bf16, 128x32 = 512 x 16B chunks) ----
    #pragma unroll
    for (int c = 0; c < 2; ++c){
      const int q0 = ((w << 1) | c) << 6;          // wave-uniform chunk base
      const int q  = q0 | lane;
      const u16* gp = A + (arow + (q >> 2)) * (long)K + kt + ((q & 3) << 3);
      GLOAD_LDS16(gp, As + q0 * 8);
    }
    // ---- stage B (fp32 -> bf16, transpose into Bs[col][k]) ----
    {
      const float* bp = B + (long)(kt + bk0) * N + (long)bn * 128 + bc0;
      const float4 r0 = *(const float4*)bp;
      const float4 r1 = *(const float4*)(bp + N);
      const float4 r2 = *(const float4*)(bp + 2 * N);
      const float4 r3 = *(const float4*)(bp + 3 * N);
      const float rr[4][4] = {{r0.x,r0.y,r0.z,r0.w},{r1.x,r1.y,r1.z,r1.w},
                              {r2.x,r2.y,r2.z,r2.w},{r3.x,r3.y,r3.z,r3.w}};
      #pragma unroll
      for (int j = 0; j < 4; ++j){
        uint2 pk;
        pk.x = (u32)f2bf(rr[0][j]) | ((u32)f2bf(rr[1][j]) << 16);
        pk.y = (u32)f2bf(rr[2][j]) | ((u32)f2bf(rr[3][j]) << 16);
        *(uint2*)(Bs + (bc0 + j) * 40 + bk0) = pk;
      }
    }
    __syncthreads();
    // ---- 16 MFMA ----
    bf16x8 af[4], bfr[4];
    #pragma unroll
    for (int i = 0; i < 4; ++i)
      af[i] = ld8(As + (wr * 64 + i * 16 + l15) * 32 + g * 8);
    #pragma unroll
    for (int i = 0; i < 4; ++i)
      bfr[i] = ld8(Bs + (wc * 64 + i * 16 + l15) * 40 + g * 8);
    #pragma unroll
    for (int mi = 0; mi < 4; ++mi)
      #pragma unroll
      for (int ni = 0; ni < 4; ++ni)
        acc[mi][ni] = mfma16(af[mi], bfr[ni], acc[mi][ni]);
  }
  // ---- epilogue: C/D frag: col = l15, row = g*4 + r ----
  const int row0 = bm * 128 + wr * 64, col0 = bn * 128 + wc * 64;
  #pragma unroll
  for (int mi = 0; mi < 4; ++mi){
    #pragma unroll
    for (int ni = 0; ni < 4; ++ni){
      #pragma unroll
      for (int r = 0; r < 4; ++r){
        const long ri = row0 + mi * 16 + g * 4 + r;
        const long ci = col0 + ni * 16 + l15;
        float v = acc[mi][ni][r];
        if (RES) v += Rs[ri * N + ci];
        if (OUT_BF16) ((u16*)C)[ri * N + ci] = f2bf(v);
        else          ((float*)C)[ri * N + ci] = v;
      }
    }
  }
}

// -------------------- RoPE in-place on bf16 qkv (q heads + k heads) --------------------
__global__ void k_rope(u16* __restrict__ qkv){
  const int idx = blockIdx.x * 256 + threadIdx.x;   // S * 20 * 64
  const int i = idx & 63;                 // pair index (dims 2i, 2i+1)
  const int head = (idx >> 6) % 20;       // 0..15 q heads, 16..19 k heads
  const int s = idx / (64 * 20);
  const long base = (long)s * NQKV + (head < NHQ ? head * HDIM : DMODEL + (head - NHQ) * HDIM);
  u32* p = (u32*)(qkv + base + 2 * i);
  const u32 v = *p;
  const float x0 = bf2f((u16)(v & 0xffffu)), x1 = bf2f((u16)(v >> 16));
  // inv = theta^(-i/64) = exp2(-log2(theta)/64 * i); log2(500000)/64 = 0.29580575889569023
  const float ang = (float)s * exp2f(-0.29580575889569023f * (float)i);
  float sn, cs;
  sincosf(ang, &sn, &cs);
  const float y0 = x0 * cs - x1 * sn;
  const float y1 = x0 * sn + x1 * cs;
  *p = (u32)f2bf(y0) | ((u32)f2bf(y1) << 16);
}

// -------------------- Flash attention (causal, GQA) --------------------
// block = (qb, h): 64 q rows, 4 waves x 16 rows. KV tiles of 64.
__global__ __launch_bounds__(256) void k_attn(const u16* __restrict__ qkv, u16* __restrict__ o){
  const int qb = blockIdx.x, h = blockIdx.y;
  const int kh = h >> 2;                      // GQA: G=4
  const int t = threadIdx.x, w = t >> 6, lane = t & 63, l15 = lane & 15, g = lane >> 4;
  __shared__ u16 Ks[64 * 144];    // [kv][d], stride 144 (pad)
  __shared__ u16 Vt[128 * 80];    // [d][kv], stride 80 (pad)
  __shared__ u16 Ps[4][16 * 72];  // per-wave P, stride 72 (pad)
  const int q0 = qb * 64 + w * 16;
  bf16x8 aq[4];
  #pragma unroll
  for (int d0 = 0; d0 < 4; ++d0)
    aq[d0] = ld8(qkv + (long)(q0 + l15) * NQKV + h * HDIM + d0 * 32 + g * 8);
  f32x4 acc_o[8] = {};
  float mst[4], lst[4];
  #pragma unroll
  for (int r = 0; r < 4; ++r){ mst[r] = -1e30f; lst[r] = 0.f; }
  const float scale = 0.08838834764831843f;   // 1/sqrt(128)
  const int krow = t >> 2, kc0 = (t & 3) << 5;
  const int vkv = (t & 31) << 1, vd0 = (t >> 5) << 4;
  for (int kt = 0; kt <= qb; ++kt){
    const int kv0 = kt << 6;
    __syncthreads();
    { // stage K tile [64][128]
      const u16* kp = qkv + (long)(kv0 + krow) * NQKV + DMODEL + kh * HDIM + kc0;
      u16* kd = Ks + krow * 144 + kc0;
      #pragma unroll
      for (int c = 0; c < 4; ++c)
        *(uint4*)(kd + c * 8) = *(const uint4*)(kp + c * 8);
    }
    { // stage V transposed: Vt[d][kv]
      const u16* vp = qkv + (long)(kv0 + vkv) * NQKV + DMODEL + 512 + kh * HDIM + vd0;
      const uint4 a0 = *(const uint4*)vp;
      const uint4 a1 = *(const uint4*)(vp + 8);
      const uint4 b0 = *(const uint4*)(vp + NQKV);
      const uint4 b1 = *(const uint4*)(vp + NQKV + 8);
      const u32 aw[8] = {a0.x,a0.y,a0.z,a0.w,a1.x,a1.y,a1.z,a1.w};
      const u32 bw[8] = {b0.x,b0.y,b0.z,b0.w,b1.x,b1.y,b1.z,b1.w};
      #pragma unroll
      for (int i2 = 0; i2 < 8; ++i2){
        *(u32*)(Vt + (vd0 + 2 * i2)     * 80 + vkv) = (aw[i2] & 0xffffu) | ((bw[i2] & 0xffffu) << 16);
        *(u32*)(Vt + (vd0 + 2 * i2 + 1) * 80 + vkv) = (aw[i2] >> 16)     | ((bw[i2] >> 16) << 16);
      }
    }
    __syncthreads();
    // ---- S = Q K^T ----
    f32x4 sacc[4] = {};
    #pragma unroll
    for (int d0 = 0; d0 < 4; ++d0){
      #pragma unroll
      for (int j = 0; j < 4; ++j){
        const bf16x8 bk = ld8(Ks + (j * 16 + l15) * 144 + d0 * 32 + g * 8);
        sacc[j] = mfma16(aq[d0], bk, sacc[j]);
      }
    }
    // ---- mask + online softmax (rows live in 16-lane groups) ----
    float p[4][4], scl[4];
    #pragma unroll
    for (int r = 0; r < 4; ++r){
      const int qrow = q0 + g * 4 + r;
      float mx = -1e30f;
      #pragma unroll
      for (int j = 0; j < 4; ++j){
        float sv = sacc[j][r] * scale;
        sv = (kv0 + j * 16 + l15 <= qrow) ? sv : -1e30f;
        p[j][r] = sv;
        mx = fmaxf(mx, sv);
      }
      #pragma unroll
      for (int off = 1; off < 16; off <<= 1) mx = fmaxf(mx, __shfl_xor(mx, off, 64));
      const float mnew = fmaxf(mst[r], mx);
      scl[r] = __expf(mst[r] - mnew);
      float rs = 0.f;
      #pragma unroll
      for (int j = 0; j < 4; ++j){ p[j][r] = __expf(p[j][r] - mnew); rs += p[j][r]; }
      #pragma unroll
      for (int off = 1; off < 16; off <<= 1) rs += __shfl_xor(rs, off, 64);
      lst[r] = lst[r] * scl[r] + rs;
      mst[r] = mnew;
    }
    #pragma unroll
    for (int n = 0; n < 8; ++n)
      #pragma unroll
      for (int r = 0; r < 4; ++r)
        acc_o[n][r] *= scl[r];
    // ---- P -> LDS (per-wave), then PV ----
    #pragma unroll
    for (int j = 0; j < 4; ++j)
      #pragma unroll
      for (int r = 0; r < 4; ++r)
        Ps[w][(g * 4 + r) * 72 + j * 16 + l15] = f2bf(p[j][r]);
    #pragma unroll
    for (int kk = 0; kk < 2; ++kk){
      const bf16x8 pa = ld8(Ps[w] + l15 * 72 + kk * 32 + g * 8);
      #pragma unroll
      for (int n = 0; n < 8; ++n){
        const bf16x8 bv = ld8(Vt + (n * 16 + l15) * 80 + kk * 32 + g * 8);
        acc_o[n] = mfma16(pa, bv, acc_o[n]);
      }
    }
  }
  // ---- epilogue: o[s][h*128 + d] ----
  #pragma unroll
  for (int n = 0; n < 8; ++n){
    #pragma unroll
    for (int r = 0; r < 4; ++r){
      const float ov = acc_o[n][r] / lst[r];
      o[(long)(q0 + g * 4 + r) * DMODEL + h * HDIM + n * 16 + l15] = f2bf(ov);
    }
  }
}

// -------------------- SwiGLU: silu(gate)*up --------------------
__global__ void k_swiglu(const u16* __restrict__ gu, u16* __restrict__ out){
  const long idx = ((long)blockIdx.x * 256 + threadIdx.x) * 8;  // in S*P elements
  const long s = idx >> 13;
  const int j = (int)(idx & 8191);
  const u16* gp = gu + s * 16384 + j;
  const uint4 gv = *(const uint4*)gp;
  const uint4 uv = *(const uint4*)(gp + PDIM);
  const u32 gw[4] = {gv.x, gv.y, gv.z, gv.w};
  const u32 uw[4] = {uv.x, uv.y, uv.z, uv.w};
  u32 ow[4];
  #pragma unroll
  for (int k = 0; k < 4; ++k){
    const float g0 = bf2f((u16)(gw[k] & 0xffffu)), g1 = bf2f((u16)(gw[k] >> 16));
    const float u0 = bf2f((u16)(uw[k] & 0xffffu)), u1 = bf2f((u16)(uw[k] >> 16));
    const float s0 = g0 / (1.f + __expf(-g0)) * u0;
    const float s1 = g1 / (1.f + __expf(-g1)) * u1;
    ow[k] = (u32)f2bf(s0) | ((u32)f2bf(s1) << 16);
  }
  uint4 ro; ro.x = ow[0]; ro.y = ow[1]; ro.z = ow[2]; ro.w = ow[3];
  *(uint4*)(out + idx) = ro;
}

// -------------------- launch --------------------
extern "C" void kernel_launch(void* const* d_in, const int* in_sizes, int n_in,
                              void* d_out, int out_size, void* d_ws, size_t ws_size,
                              hipStream_t stream){
  const int*   tokens       = (const int*)d_in[0];
  const float* embed        = (const float*)d_in[1];
  const float* attn_norm_w  = (const float*)d_in[2];
  const float* qkv_w        = (const float*)d_in[3];
  const float* attn_out_w   = (const float*)d_in[4];
  const float* mlp_norm_w   = (const float*)d_in[5];
  const float* mlp_in_w     = (const float*)d_in[6];
  const float* mlp_out_w    = (const float*)d_in[7];
  const float* final_norm_w = (const float*)d_in[8];
  const float* lm_head_w    = (const float*)d_in[9];

  char* ws = (char*)d_ws;                       // total use: ~140 MB
  float* xf  = (float*)(ws);                    // 16 MB  residual (fp32)
  u16* hbf   = (u16*)(ws + 16777216);           //  8 MB  normed activations (bf16)
  u16* qkvb  = (u16*)(ws + 25165824);           // 12 MB  qkv (bf16)
  u16* obf   = (u16*)(ws + 37748736);           //  8 MB  attn out (bf16)
  u16* gub   = (u16*)(ws + 46137344);           // 64 MB  gate|up (bf16)
  u16* hb2   = (u16*)(ws + 113246208);          // 32 MB  silu(g)*u (bf16)

  k_embed<<<S_LEN, 256, 0, stream>>>(tokens, embed, xf);
  for (int l = 0; l < 2; ++l){
    k_rmsnorm<<<S_LEN, 256, 0, stream>>>(xf, attn_norm_w + (long)l * DMODEL, hbf);
    k_gemm<1,0><<<dim3(NQKV/128, S_LEN/128), 256, 0, stream>>>(
        hbf, qkv_w + (long)l * DMODEL * NQKV, qkvb, nullptr, S_LEN, NQKV, DMODEL);
    k_rope<<<(S_LEN * 20 * 64) / 256, 256, 0, stream>>>(qkvb);
    k_attn<<<dim3(S_LEN/64, NHQ), 256, 0, stream>>>(qkvb, obf);
    k_gemm<0,1><<<dim3(DMODEL/128, S_LEN/128), 256, 0, stream>>>(
        obf, attn_out_w + (long)l * DMODEL * DMODEL, xf, xf, S_LEN, DMODEL, DMODEL);
    k_rmsnorm<<<S_LEN, 256, 0, stream>>>(xf, mlp_norm_w + (long)l * DMODEL, hbf);
    k_gemm<1,0><<<dim3((2*PDIM)/128, S_LEN/128), 256, 0, stream>>>(
        hbf, mlp_in_w + (long)l * DMODEL * 2 * PDIM, gub, nullptr, S_LEN, 2*PDIM, DMODEL);
    k_swiglu<<<(S_LEN * PDIM / 8) / 256, 256, 0, stream>>>(gub, hb2);
    k_gemm<0,1><<<dim3(DMODEL/128, S_LEN/128), 256, 0, stream>>>(
        hb2, mlp_out_w + (long)l * PDIM * DMODEL, xf, xf, S_LEN, DMODEL, PDIM);
  }
  k_rmsnorm<<<S_LEN, 256, 0, stream>>>(xf, final_norm_w, hbf);
  k_gemm<0,0><<<dim3(VOCAB/128, S_LEN/128), 256, 0, stream>>>(
      hbf, lm_head_w, (float*)d_out, nullptr, S_LEN, VOCAB, DMODEL);
}

// Round 2
// 1815.151 us; speedup vs baseline: 1.4977x; 1.4977x over previous
//
#include <hip/hip_runtime.h>
#include <math.h>

#define S_LEN 2048
#define DMODEL 2048
#define NHQ 16
#define NHK 4
#define HDIM 128
#define PDIM 8192
#define VOCAB 32000
#define NQKV 3072          // D + 2*HK*HD
#define EPSI 1e-5f

typedef unsigned short u16;
typedef unsigned int u32;
typedef __bf16 bf16x8 __attribute__((ext_vector_type(8)));
typedef float f32x4 __attribute__((ext_vector_type(4)));

__device__ __forceinline__ u16 f2bf(float f){
  u32 u = __builtin_bit_cast(u32, f);
  u += 0x7fffu + ((u >> 16) & 1u);   // RNE
  return (u16)(u >> 16);
}
__device__ __forceinline__ float bf2f(u16 h){
  u32 u = ((u32)h) << 16;
  return __builtin_bit_cast(float, u);
}
__device__ __forceinline__ bf16x8 ld8(const u16* p){
  return __builtin_bit_cast(bf16x8, *(const uint4*)p);
}
__device__ __forceinline__ f32x4 mfma16(bf16x8 a, bf16x8 b, f32x4 c){
  return __builtin_amdgcn_mfma_f32_16x16x32_bf16(a, b, c, 0, 0, 0);
}

#define GLOAD_LDS16(gp, lp) __builtin_amdgcn_global_load_lds( \
    (__attribute__((address_space(1))) void*)(gp), \
    (__attribute__((address_space(3))) void*)(lp), 16, 0, 0)

// -------------------- embed gather --------------------
__global__ void k_embed(const int* __restrict__ tok, const float* __restrict__ emb,
                        float* __restrict__ x){
  const int s = blockIdx.x, t = threadIdx.x;
  const long r = tok[s];
  const float4* src = (const float4*)(emb + r * DMODEL);
  float4* dst = (float4*)(x + (long)s * DMODEL);
  dst[t] = src[t];
  dst[t + 256] = src[t + 256];
}

// -------------------- RMSNorm: fp32 in -> bf16 out --------------------
__global__ void k_rmsnorm(const float* __restrict__ x, const float* __restrict__ w,
                          u16* __restrict__ out){
  const int s = blockIdx.x, t = threadIdx.x;
  const float4* xr = (const float4*)(x + (long)s * DMODEL);
  const float4 a = xr[t], b = xr[t + 256];
  float ss = a.x*a.x + a.y*a.y + a.z*a.z + a.w*a.w
           + b.x*b.x + b.y*b.y + b.z*b.z + b.w*b.w;
  #pragma unroll
  for (int off = 32; off > 0; off >>= 1) ss += __shfl_down(ss, off, 64);
  __shared__ float part[4];
  if ((t & 63) == 0) part[t >> 6] = ss;
  __syncthreads();
  const float r = rsqrtf((part[0] + part[1] + part[2] + part[3]) * (1.f / 2048.f) + EPSI);
  const float4* wr = (const float4*)w;
  const float4 wa = wr[t], wb = wr[t + 256];
  uint2 ua, ub;
  ua.x = (u32)f2bf(a.x*r*wa.x) | ((u32)f2bf(a.y*r*wa.y) << 16);
  ua.y = (u32)f2bf(a.z*r*wa.z) | ((u32)f2bf(a.w*r*wa.w) << 16);
  ub.x = (u32)f2bf(b.x*r*wb.x) | ((u32)f2bf(b.y*r*wb.y) << 16);
  ub.y = (u32)f2bf(b.z*r*wb.z) | ((u32)f2bf(b.w*r*wb.w) << 16);
  *(uint2*)(out + (long)s * DMODEL + 4 * t) = ua;
  *(uint2*)(out + (long)s * DMODEL + 1024 + 4 * t) = ub;
}

// -------------------- weight convert + transpose: W f32[K][N] -> Wt bf16[N][K] ---
__global__ __launch_bounds__(256) void k_convT(const float* __restrict__ W,
                                               u16* __restrict__ Wt, int N, int K){
  const int n0 = blockIdx.x * 64, k0 = blockIdx.y * 64;
  const int t = threadIdx.x;
  __shared__ u16 T[64][72];    // [n][k], padded
  const int r = t >> 4, c = (t & 15) << 2;
  #pragma unroll
  for (int p = 0; p < 4; ++p){
    const int k = p * 16 + r;
    const float4 v = *(const float4*)(W + (long)(k0 + k) * N + n0 + c);
    T[c + 0][k] = f2bf(v.x);
    T[c + 1][k] = f2bf(v.y);
    T[c + 2][k] = f2bf(v.z);
    T[c + 3][k] = f2bf(v.w);
  }
  __syncthreads();
  const int nr = t >> 3, kc = (t & 7) << 3;
  #pragma unroll
  for (int p = 0; p < 2; ++p){
    const int n = p * 32 + nr;
    *(uint4*)(Wt + (long)(n0 + n) * K + k0 + kc) = *(const uint4*)(&T[n][kc]);
  }
}

// -------------------- GEMM: C[M,N] = A_bf16[M,K] @ Bt_bf16[N,K]^T --------------------
// m97 structure: 128x128 tile, BK=32, 4 waves; A and B both via global_load_lds w16.
template<int OUT_BF16, int RES>
__global__ __launch_bounds__(256) void k_gemm(const u16* __restrict__ A, const u16* __restrict__ Bt,
                                              void* C, const float* Rs,
                                              int M, int N, int K){
  const int bm = blockIdx.x, bn = blockIdx.y;   // x = bm: concurrent window shares B panels
  const int t = threadIdx.x;
  const int w = t >> 6, lane = t & 63, l15 = lane & 15, g = lane >> 4;
  const int wr = w >> 1, wc = w & 1;
  __shared__ u16 As[128 * 32];    // linear [row][k]
  __shared__ u16 Bs[128 * 32];    // linear [col][k]
  f32x4 acc[4][4] = {};
  const long arow = (long)bm * 128;
  const long brow = (long)bn * 128;
  for (int kt = 0; kt < K; kt += 32){
    __syncthreads();
    #pragma unroll
    for (int c = 0; c < 2; ++c){
      const int q0 = ((w << 1) | c) << 6;          // wave-uniform chunk base
      const int q  = q0 | lane;
      const u16* gpa = A  + (arow + (q >> 2)) * (long)K + kt + ((q & 3) << 3);
      const u16* gpb = Bt + (brow + (q >> 2)) * (long)K + kt + ((q & 3) << 3);
      GLOAD_LDS16(gpa, As + q0 * 8);
      GLOAD_LDS16(gpb, Bs + q0 * 8);
    }
    __syncthreads();
    bf16x8 af[4], bfr[4];
    #pragma unroll
    for (int i = 0; i < 4; ++i)
      af[i] = ld8(As + (wr * 64 + i * 16 + l15) * 32 + g * 8);
    #pragma unroll
    for (int i = 0; i < 4; ++i)
      bfr[i] = ld8(Bs + (wc * 64 + i * 16 + l15) * 32 + g * 8);
    #pragma unroll
    for (int mi = 0; mi < 4; ++mi)
      #pragma unroll
      for (int ni = 0; ni < 4; ++ni)
        acc[mi][ni] = mfma16(af[mi], bfr[ni], acc[mi][ni]);
  }
  // epilogue: C/D frag: col = l15, row = g*4 + r
  const int row0 = bm * 128 + wr * 64, col0 = bn * 128 + wc * 64;
  #pragma unroll
  for (int mi = 0; mi < 4; ++mi){
    #pragma unroll
    for (int ni = 0; ni < 4; ++ni){
      #pragma unroll
      for (int r = 0; r < 4; ++r){
        const long ri = row0 + mi * 16 + g * 4 + r;
        const long ci = col0 + ni * 16 + l15;
        float v = acc[mi][ni][r];
        if (RES) v += Rs[ri * N + ci];
        if (OUT_BF16) ((u16*)C)[ri * N + ci] = f2bf(v);
        else          ((float*)C)[ri * N + ci] = v;
      }
    }
  }
}

// -------------------- RoPE in-place on bf16 qkv (q heads + k heads) --------------------
__global__ void k_rope(u16* __restrict__ qkv){
  const int idx = blockIdx.x * 256 + threadIdx.x;   // S * 20 * 64
  const int i = idx & 63;                 // pair index (dims 2i, 2i+1)
  const int head = (idx >> 6) % 20;       // 0..15 q heads, 16..19 k heads
  const int s = idx / (64 * 20);
  const long base = (long)s * NQKV + (head < NHQ ? head * HDIM : DMODEL + (head - NHQ) * HDIM);
  u32* p = (u32*)(qkv + base + 2 * i);
  const u32 v = *p;
  const float x0 = bf2f((u16)(v & 0xffffu)), x1 = bf2f((u16)(v >> 16));
  const float ang = (float)s * exp2f(-0.29580575889569023f * (float)i);
  float sn, cs;
  sincosf(ang, &sn, &cs);
  const float y0 = x0 * cs - x1 * sn;
  const float y1 = x0 * sn + x1 * cs;
  *p = (u32)f2bf(y0) | ((u32)f2bf(y1) << 16);
}

// -------------------- Flash attention (causal, GQA) --------------------
__global__ __launch_bounds__(256) void k_attn(const u16* __restrict__ qkv, u16* __restrict__ o){
  const int qb = blockIdx.x, h = blockIdx.y;
  const int kh = h >> 2;                      // GQA: G=4
  const int t = threadIdx.x, w = t >> 6, lane = t & 63, l15 = lane & 15, g = lane >> 4;
  __shared__ u16 Ks[64 * 144];    // [kv][d], stride 144 (pad)
  __shared__ u16 Vt[128 * 80];    // [d][kv], stride 80 (pad)
  __shared__ u16 Ps[4][16 * 72];  // per-wave P, stride 72 (pad)
  const int q0 = qb * 64 + w * 16;
  bf16x8 aq[4];
  #pragma unroll
  for (int d0 = 0; d0 < 4; ++d0)
    aq[d0] = ld8(qkv + (long)(q0 + l15) * NQKV + h * HDIM + d0 * 32 + g * 8);
  f32x4 acc_o[8] = {};
  float mst[4], lst[4];
  #pragma unroll
  for (int r = 0; r < 4; ++r){ mst[r] = -1e30f; lst[r] = 0.f; }
  const float scale = 0.08838834764831843f;   // 1/sqrt(128)
  const int krow = t >> 2, kc0 = (t & 3) << 5;
  const int vkv = (t & 31) << 1, vd0 = (t >> 5) << 4;
  for (int kt = 0; kt <= qb; ++kt){
    const int kv0 = kt << 6;
    __syncthreads();
    { // stage K tile [64][128]
      const u16* kp = qkv + (long)(kv0 + krow) * NQKV + DMODEL + kh * HDIM + kc0;
      u16* kd = Ks + krow * 144 + kc0;
      #pragma unroll
      for (int c = 0; c < 4; ++c)
        *(uint4*)(kd + c * 8) = *(const uint4*)(kp + c * 8);
    }
    { // stage V transposed: Vt[d][kv]
      const u16* vp = qkv + (long)(kv0 + vkv) * NQKV + DMODEL + 512 + kh * HDIM + vd0;
      const uint4 a0 = *(const uint4*)vp;
      const uint4 a1 = *(const uint4*)(vp + 8);
      const uint4 b0 = *(const uint4*)(vp + NQKV);
      const uint4 b1 = *(const uint4*)(vp + NQKV + 8);
      const u32 aw[8] = {a0.x,a0.y,a0.z,a0.w,a1.x,a1.y,a1.z,a1.w};
      const u32 bw[8] = {b0.x,b0.y,b0.z,b0.w,b1.x,b1.y,b1.z,b1.w};
      #pragma unroll
      for (int i2 = 0; i2 < 8; ++i2){
        *(u32*)(Vt + (vd0 + 2 * i2)     * 80 + vkv) = (aw[i2] & 0xffffu) | ((bw[i2] & 0xffffu) << 16);
        *(u32*)(Vt + (vd0 + 2 * i2 + 1) * 80 + vkv) = (aw[i2] >> 16)     | ((bw[i2] >> 16) << 16);
      }
    }
    __syncthreads();
    // ---- S = Q K^T ----
    f32x4 sacc[4] = {};
    #pragma unroll
    for (int d0 = 0; d0 < 4; ++d0){
      #pragma unroll
      for (int j = 0; j < 4; ++j){
        const bf16x8 bk = ld8(Ks + (j * 16 + l15) * 144 + d0 * 32 + g * 8);
        sacc[j] = mfma16(aq[d0], bk, sacc[j]);
      }
    }
    // ---- mask + online softmax ----
    float p[4][4], scl[4];
    #pragma unroll
    for (int r = 0; r < 4; ++r){
      const int qrow = q0 + g * 4 + r;
      float mx = -1e30f;
      #pragma unroll
      for (int j = 0; j < 4; ++j){
        float sv = sacc[j][r] * scale;
        sv = (kv0 + j * 16 + l15 <= qrow) ? sv : -1e30f;
        p[j][r] = sv;
        mx = fmaxf(mx, sv);
      }
      #pragma unroll
      for (int off = 1; off < 16; off <<= 1) mx = fmaxf(mx, __shfl_xor(mx, off, 64));
      const float mnew = fmaxf(mst[r], mx);
      scl[r] = __expf(mst[r] - mnew);
      float rs = 0.f;
      #pragma unroll
      for (int j = 0; j < 4; ++j){ p[j][r] = __expf(p[j][r] - mnew); rs += p[j][r]; }
      #pragma unroll
      for (int off = 1; off < 16; off <<= 1) rs += __shfl_xor(rs, off, 64);
      lst[r] = lst[r] * scl[r] + rs;
      mst[r] = mnew;
    }
    #pragma unroll
    for (int n = 0; n < 8; ++n)
      #pragma unroll
      for (int r = 0; r < 4; ++r)
        acc_o[n][r] *= scl[r];
    // ---- P -> LDS (per-wave), then PV ----
    #pragma unroll
    for (int j = 0; j < 4; ++j)
      #pragma unroll
      for (int r = 0; r < 4; ++r)
        Ps[w][(g * 4 + r) * 72 + j * 16 + l15] = f2bf(p[j][r]);
    #pragma unroll
    for (int kk = 0; kk < 2; ++kk){
      const bf16x8 pa = ld8(Ps[w] + l15 * 72 + kk * 32 + g * 8);
      #pragma unroll
      for (int n = 0; n < 8; ++n){
        const bf16x8 bv = ld8(Vt + (n * 16 + l15) * 80 + kk * 32 + g * 8);
        acc_o[n] = mfma16(pa, bv, acc_o[n]);
      }
    }
  }
  #pragma unroll
  for (int n = 0; n < 8; ++n){
    #pragma unroll
    for (int r = 0; r < 4; ++r){
      const float ov = acc_o[n][r] / lst[r];
      o[(long)(q0 + g * 4 + r) * DMODEL + h * HDIM + n * 16 + l15] = f2bf(ov);
    }
  }
}

// -------------------- SwiGLU: silu(gate)*up --------------------
__global__ void k_swiglu(const u16* __restrict__ gu, u16* __restrict__ out){
  const long idx = ((long)blockIdx.x * 256 + threadIdx.x) * 8;  // in S*P elements
  const long s = idx >> 13;
  const int j = (int)(idx & 8191);
  const u16* gp = gu + s * 16384 + j;
  const uint4 gv = *(const uint4*)gp;
  const uint4 uv = *(const uint4*)(gp + PDIM);
  const u32 gw[4] = {gv.x, gv.y, gv.z, gv.w};
  const u32 uw[4] = {uv.x, uv.y, uv.z, uv.w};
  u32 ow[4];
  #pragma unroll
  for (int k = 0; k < 4; ++k){
    const float g0 = bf2f((u16)(gw[k] & 0xffffu)), g1 = bf2f((u16)(gw[k] >> 16));
    const float u0 = bf2f((u16)(uw[k] & 0xffffu)), u1 = bf2f((u16)(uw[k] >> 16));
    const float s0 = g0 / (1.f + __expf(-g0)) * u0;
    const float s1 = g1 / (1.f + __expf(-g1)) * u1;
    ow[k] = (u32)f2bf(s0) | ((u32)f2bf(s1) << 16);
  }
  uint4 ro; ro.x = ow[0]; ro.y = ow[1]; ro.z = ow[2]; ro.w = ow[3];
  *(uint4*)(out + idx) = ro;
}

// -------------------- launch --------------------
extern "C" void kernel_launch(void* const* d_in, const int* in_sizes, int n_in,
                              void* d_out, int out_size, void* d_ws, size_t ws_size,
                              hipStream_t stream){
  const int*   tokens       = (const int*)d_in[0];
  const float* embed        = (const float*)d_in[1];
  const float* attn_norm_w  = (const float*)d_in[2];
  const float* qkv_w        = (const float*)d_in[3];
  const float* attn_out_w   = (const float*)d_in[4];
  const float* mlp_norm_w   = (const float*)d_in[5];
  const float* mlp_in_w     = (const float*)d_in[6];
  const float* mlp_out_w    = (const float*)d_in[7];
  const float* final_norm_w = (const float*)d_in[8];
  const float* lm_head_w    = (const float*)d_in[9];

  char* ws = (char*)d_ws;
  float* xf  = (float*)(ws);                    // 16.78 MB residual (fp32)
  u16* hbf   = (u16*)(ws + 16777216);           //  8.39 MB normed activations (bf16)
  u16* qkvb  = (u16*)(ws + 25165824);           // 12.58 MB qkv (bf16)
  u16* obf   = (u16*)(ws + 37748736);           //  8.39 MB attn out (bf16)
  u16* gub   = (u16*)(ws + 46137344);           // 67.11 MB gate|up (bf16)
  u16* hb2   = (u16*)(ws + 113246208);          // 33.55 MB silu(g)*u (bf16)
  u16* wbuf  = (u16*)(ws + 146800640);          // 131.07 MB transposed bf16 weights
                                                // total: 277.9 MB

  k_embed<<<S_LEN, 256, 0, stream>>>(tokens, embed, xf);
  for (int l = 0; l < 2; ++l){
    k_rmsnorm<<<S_LEN, 256, 0, stream>>>(xf, attn_norm_w + (long)l * DMODEL, hbf);
    k_convT<<<dim3(NQKV/64, DMODEL/64), 256, 0, stream>>>(
        qkv_w + (long)l * DMODEL * NQKV, wbuf, NQKV, DMODEL);
    k_gemm<1,0><<<dim3(S_LEN/128, NQKV/128), 256, 0, stream>>>(
        hbf, wbuf, qkvb, nullptr, S_LEN, NQKV, DMODEL);
    k_rope<<<(S_LEN * 20 * 64) / 256, 256, 0, stream>>>(qkvb);
    k_attn<<<dim3(S_LEN/64, NHQ), 256, 0, stream>>>(qkvb, obf);
    k_convT<<<dim3(DMODEL/64, DMODEL/64), 256, 0, stream>>>(
        attn_out_w + (long)l * DMODEL * DMODEL, wbuf, DMODEL, DMODEL);
    k_gemm<0,1><<<dim3(S_LEN/128, DMODEL/128), 256, 0, stream>>>(
        obf, wbuf, xf, xf, S_LEN, DMODEL, DMODEL);
    k_rmsnorm<<<S_LEN, 256, 0, stream>>>(xf, mlp_norm_w + (long)l * DMODEL, hbf);
    k_convT<<<dim3((2*PDIM)/64, DMODEL/64), 256, 0, stream>>>(
        mlp_in_w + (long)l * DMODEL * 2 * PDIM, wbuf, 2*PDIM, DMODEL);
    k_gemm<1,0><<<dim3(S_LEN/128, (2*PDIM)/128), 256, 0, stream>>>(
        hbf, wbuf, gub, nullptr, S_LEN, 2*PDIM, DMODEL);
    k_swiglu<<<(S_LEN * PDIM / 8) / 256, 256, 0, stream>>>(gub, hb2);
    k_convT<<<dim3(DMODEL/64, PDIM/64), 256, 0, stream>>>(
        mlp_out_w + (long)l * PDIM * DMODEL, wbuf, DMODEL, PDIM);
    k_gemm<0,1><<<dim3(S_LEN/128, DMODEL/128), 256, 0, stream>>>(
        hb2, wbuf, xf, xf, S_LEN, DMODEL, PDIM);
  }
  k_rmsnorm<<<S_LEN, 256, 0, stream>>>(xf, final_norm_w, hbf);
  k_convT<<<dim3(VOCAB/64, DMODEL/64), 256, 0, stream>>>(lm_head_w, wbuf, VOCAB, DMODEL);
  k_gemm<0,0><<<dim3(S_LEN/128, VOCAB/128), 256, 0, stream>>>(
      hbf, wbuf, (float*)d_out, nullptr, S_LEN, VOCAB, DMODEL);
}

// Round 3
// 1625.282 us; speedup vs baseline: 1.6727x; 1.1168x over previous
//
#include <hip/hip_runtime.h>
#include <math.h>

#define S_LEN 2048
#define DMODEL 2048
#define NHQ 16
#define NHK 4
#define HDIM 128
#define PDIM 8192
#define VOCAB 32000
#define NQKV 3072          // D + 2*HK*HD
#define EPSI 1e-5f

typedef unsigned short u16;
typedef unsigned int u32;
typedef __bf16 bf16x8 __attribute__((ext_vector_type(8)));
typedef float f32x4 __attribute__((ext_vector_type(4)));

__device__ __forceinline__ u16 f2bf(float f){
  u32 u = __builtin_bit_cast(u32, f);
  u += 0x7fffu + ((u >> 16) & 1u);   // RNE
  return (u16)(u >> 16);
}
__device__ __forceinline__ float bf2f(u16 h){
  u32 u = ((u32)h) << 16;
  return __builtin_bit_cast(float, u);
}
__device__ __forceinline__ bf16x8 ld8(const u16* p){
  return __builtin_bit_cast(bf16x8, *(const uint4*)p);
}
__device__ __forceinline__ f32x4 mfma16(bf16x8 a, bf16x8 b, f32x4 c){
  return __builtin_amdgcn_mfma_f32_16x16x32_bf16(a, b, c, 0, 0, 0);
}

#define GLOAD_LDS16(gp, lp) __builtin_amdgcn_global_load_lds( \
    (__attribute__((address_space(1))) void*)(gp), \
    (__attribute__((address_space(3))) void*)(lp), 16, 0, 0)

// Swizzled LDS tile layout (shared by both GEMMs):
// a [Rows][32] bf16 tile is stored as row-PAIRS: LDS line Rp = R>>1 holds
// rows {2Rp, 2Rp+1} x 32 cols = 128 B = 8 slots of 16 B. Slot content is
// XOR-permuted by (Rp&7) so that frag ds_read_b128 spreads over all 32 banks
// (2-way = free). global_load_lds dest stays LINEAR; the permutation is
// applied to the per-lane GLOBAL source address (involution both sides).
__device__ __forceinline__ bf16x8 lds_frag(const u16* Lb, int R, int g){
  const int Rp = R >> 1;
  const int s8 = (((R & 1) << 2) | g) ^ (Rp & 7);
  return ld8(Lb + Rp * 64 + s8 * 8);
}
// chunk q (16B units): Rp=q>>3, swizzled slot -> global (row, kcol)
__device__ __forceinline__ void stage_sw(const u16* base, long row0, int K, int kt,
                                         int q, u16* Ldst_waveuniform){
  const int Rp = q >> 3;
  const int u = (q & 7) ^ (Rp & 7);
  const int R = (Rp << 1) | (u >> 2);
  const u16* gp = base + (row0 + R) * (long)K + kt + ((u & 3) << 3);
  GLOAD_LDS16(gp, Ldst_waveuniform);
}

// -------------------- embed gather --------------------
__global__ void k_embed(const int* __restrict__ tok, const float* __restrict__ emb,
                        float* __restrict__ x){
  const int s = blockIdx.x, t = threadIdx.x;
  const long r = tok[s];
  const float4* src = (const float4*)(emb + r * DMODEL);
  float4* dst = (float4*)(x + (long)s * DMODEL);
  dst[t] = src[t];
  dst[t + 256] = src[t + 256];
}

// -------------------- RMSNorm: fp32 in -> bf16 out --------------------
__global__ void k_rmsnorm(const float* __restrict__ x, const float* __restrict__ w,
                          u16* __restrict__ out){
  const int s = blockIdx.x, t = threadIdx.x;
  const float4* xr = (const float4*)(x + (long)s * DMODEL);
  const float4 a = xr[t], b = xr[t + 256];
  float ss = a.x*a.x + a.y*a.y + a.z*a.z + a.w*a.w
           + b.x*b.x + b.y*b.y + b.z*b.z + b.w*b.w;
  #pragma unroll
  for (int off = 32; off > 0; off >>= 1) ss += __shfl_down(ss, off, 64);
  __shared__ float part[4];
  if ((t & 63) == 0) part[t >> 6] = ss;
  __syncthreads();
  const float r = rsqrtf((part[0] + part[1] + part[2] + part[3]) * (1.f / 2048.f) + EPSI);
  const float4* wr = (const float4*)w;
  const float4 wa = wr[t], wb = wr[t + 256];
  uint2 ua, ub;
  ua.x = (u32)f2bf(a.x*r*wa.x) | ((u32)f2bf(a.y*r*wa.y) << 16);
  ua.y = (u32)f2bf(a.z*r*wa.z) | ((u32)f2bf(a.w*r*wa.w) << 16);
  ub.x = (u32)f2bf(b.x*r*wb.x) | ((u32)f2bf(b.y*r*wb.y) << 16);
  ub.y = (u32)f2bf(b.z*r*wb.z) | ((u32)f2bf(b.w*r*wb.w) << 16);
  *(uint2*)(out + (long)s * DMODEL + 4 * t) = ua;
  *(uint2*)(out + (long)s * DMODEL + 1024 + 4 * t) = ub;
}

// -------------------- weight convert + transpose: W f32[K][N] -> Wt bf16[N][K] ---
__global__ __launch_bounds__(256) void k_convT(const float* __restrict__ W,
                                               u16* __restrict__ Wt, int N, int K){
  const int n0 = blockIdx.x * 64, k0 = blockIdx.y * 64;
  const int t = threadIdx.x;
  __shared__ u16 T[64][72];    // [n][k], padded
  const int r = t >> 4, c = (t & 15) << 2;
  #pragma unroll
  for (int p = 0; p < 4; ++p){
    const int k = p * 16 + r;
    const float4 v = *(const float4*)(W + (long)(k0 + k) * N + n0 + c);
    T[c + 0][k] = f2bf(v.x);
    T[c + 1][k] = f2bf(v.y);
    T[c + 2][k] = f2bf(v.z);
    T[c + 3][k] = f2bf(v.w);
  }
  __syncthreads();
  const int nr = t >> 3, kc = (t & 7) << 3;
  #pragma unroll
  for (int p = 0; p < 2; ++p){
    const int n = p * 32 + nr;
    *(uint4*)(Wt + (long)(n0 + n) * K + k0 + kc) = *(const uint4*)(&T[n][kc]);
  }
}

// -------------------- GEMM 128x128 (m97-structure, swizzled LDS) --------------------
template<int OUT_BF16, int RES>
__global__ __launch_bounds__(256) void k_gemm(const u16* __restrict__ A, const u16* __restrict__ Bt,
                                              void* C, const float* Rs,
                                              int M, int N, int K){
  const int bm = blockIdx.x, bn = blockIdx.y;
  const int t = threadIdx.x;
  const int w = t >> 6, lane = t & 63, l15 = lane & 15, g = lane >> 4;
  const int wr = w >> 1, wc = w & 1;
  __shared__ u16 As[4096];    // 64 rowpairs x 128B
  __shared__ u16 Bs[4096];
  f32x4 acc[4][4] = {};
  const long arow = (long)bm * 128;
  const long brow = (long)bn * 128;
  for (int kt = 0; kt < K; kt += 32){
    __syncthreads();
    #pragma unroll
    for (int c = 0; c < 2; ++c){
      const int q0 = ((w << 1) | c) << 6;          // wave-uniform chunk base
      const int q  = q0 | lane;
      stage_sw(A,  arow, K, kt, q, As + q0 * 8);
      stage_sw(Bt, brow, K, kt, q, Bs + q0 * 8);
    }
    __syncthreads();
    bf16x8 af[4], bfr[4];
    #pragma unroll
    for (int i = 0; i < 4; ++i)
      af[i] = lds_frag(As, wr * 64 + i * 16 + l15, g);
    #pragma unroll
    for (int i = 0; i < 4; ++i)
      bfr[i] = lds_frag(Bs, wc * 64 + i * 16 + l15, g);
    #pragma unroll
    for (int mi = 0; mi < 4; ++mi)
      #pragma unroll
      for (int ni = 0; ni < 4; ++ni)
        acc[mi][ni] = mfma16(af[mi], bfr[ni], acc[mi][ni]);
  }
  const int row0 = bm * 128 + wr * 64, col0 = bn * 128 + wc * 64;
  #pragma unroll
  for (int mi = 0; mi < 4; ++mi){
    #pragma unroll
    for (int ni = 0; ni < 4; ++ni){
      #pragma unroll
      for (int r = 0; r < 4; ++r){
        const long ri = row0 + mi * 16 + g * 4 + r;
        const long ci = col0 + ni * 16 + l15;
        float v = acc[mi][ni][r];
        if (RES) v += Rs[ri * N + ci];
        if (OUT_BF16) ((u16*)C)[ri * N + ci] = f2bf(v);
        else          ((float*)C)[ri * N + ci] = v;
      }
    }
  }
}

// -------------------- GEMM 256x256, 8 waves, 4-deep pipelined (T2+T4+T5) ----------
// BK=32, LDS = 4 slots x (A 16KB + B 16KB) = 128 KB. Prefetch distance 3 tiles;
// steady-state gate = vmcnt(8) (counted, never 0). lgkmcnt(0) precedes each
// barrier so no wave's pending ds_read can race a later gload_lds DMA overwrite.
template<int OUT_BF16>
__global__ __launch_bounds__(512, 2) void k_gemm256(const u16* __restrict__ A,
                                                    const u16* __restrict__ Bt,
                                                    void* C, int M, int N, int K){
  __shared__ u16 L[65536];                   // 128 KB
  const int t = threadIdx.x;
  const int w = t >> 6, lane = t & 63, l15 = lane & 15, g = lane >> 4;
  const int wr = w >> 2, wc = w & 3;         // 2M x 4N waves; per-wave out 128x64
  const int nbm = M >> 8;
  const int nwg = gridDim.x;
  int id = blockIdx.x;
  { // XCD-aware swizzle (nwg % 8 == 0 for all call sites)
    const int cpx = nwg >> 3;
    id = (id & 7) * cpx + (id >> 3);
  }
  const int bm = id % nbm, bn = id / nbm;    // bm fast: neighbors share B panel
  const long arow = (long)bm << 8, brow = (long)bn << 8;
  const int NT = K >> 5;

  // staging: one tile = A 16KB (1024 chunks) + B 16KB; 512 thr x 2 chunks each
  auto stage_tile = [&](int tile){
    const int sb = (tile & 3) * 8192;
    const int kt = tile << 5;
    #pragma unroll
    for (int i = 0; i < 2; ++i){
      const int q0 = i * 512 + (t & ~63);            // wave-uniform chunk base
      const int q  = i * 512 + t;
      stage_sw(A,  arow, K, kt, q, L + sb + q0 * 8);
      stage_sw(Bt, brow, K, kt, q, L + 32768 + sb + q0 * 8);
    }
  };

  stage_tile(0); stage_tile(1); stage_tile(2);
  asm volatile("s_waitcnt vmcnt(8)" ::: "memory");
  __builtin_amdgcn_s_barrier();

  f32x4 acc[8][4] = {};
  for (int tt = 0; tt < NT; ++tt){
    const u16* sA = L + (tt & 3) * 8192;
    const u16* sB = L + 32768 + (tt & 3) * 8192;
    bf16x8 af[4], bfr[4];
    // ---- phase 0 (m-half 0) ----
    #pragma unroll
    for (int n = 0; n < 4; ++n)
      bfr[n] = lds_frag(sB, wc * 64 + n * 16 + l15, g);
    #pragma unroll
    for (int j = 0; j < 4; ++j)
      af[j] = lds_frag(sA, wr * 128 + j * 16 + l15, g);
    if (tt + 3 < NT) stage_tile(tt + 3);
    asm volatile("s_waitcnt lgkmcnt(0)" ::: "memory");
    __builtin_amdgcn_s_barrier();
    __builtin_amdgcn_s_setprio(1);
    #pragma unroll
    for (int j = 0; j < 4; ++j)
      #pragma unroll
      for (int n = 0; n < 4; ++n)
        acc[j][n] = mfma16(af[j], bfr[n], acc[j][n]);
    __builtin_amdgcn_s_setprio(0);
    // ---- phase 1 (m-half 1) ----
    #pragma unroll
    for (int j = 0; j < 4; ++j)
      af[j] = lds_frag(sA, wr * 128 + 64 + j * 16 + l15, g);
    asm volatile("s_waitcnt lgkmcnt(0)" ::: "memory");
    if (tt + 1 < NT){
      if (tt + 3 < NT)      asm volatile("s_waitcnt vmcnt(8)" ::: "memory");
      else if (tt + 2 < NT) asm volatile("s_waitcnt vmcnt(4)" ::: "memory");
      else                  asm volatile("s_waitcnt vmcnt(0)" ::: "memory");
      __builtin_amdgcn_s_barrier();
    }
    __builtin_amdgcn_s_setprio(1);
    #pragma unroll
    for (int j = 0; j < 4; ++j)
      #pragma unroll
      for (int n = 0; n < 4; ++n)
        acc[4 + j][n] = mfma16(af[j], bfr[n], acc[4 + j][n]);
    __builtin_amdgcn_s_setprio(0);
  }
  // ---- epilogue ----
  const int row0 = bm * 256 + wr * 128, col0 = bn * 256 + wc * 64;
  #pragma unroll
  for (int mi = 0; mi < 8; ++mi){
    #pragma unroll
    for (int ni = 0; ni < 4; ++ni){
      #pragma unroll
      for (int r = 0; r < 4; ++r){
        const long ri = row0 + mi * 16 + g * 4 + r;
        const long ci = col0 + ni * 16 + l15;
        const float v = acc[mi][ni][r];
        if (OUT_BF16) ((u16*)C)[ri * N + ci] = f2bf(v);
        else          ((float*)C)[ri * N + ci] = v;
      }
    }
  }
}

// -------------------- RoPE in-place on bf16 qkv --------------------
__global__ void k_rope(u16* __restrict__ qkv){
  const int idx = blockIdx.x * 256 + threadIdx.x;   // S * 20 * 64
  const int i = idx & 63;
  const int head = (idx >> 6) % 20;
  const int s = idx / (64 * 20);
  const long base = (long)s * NQKV + (head < NHQ ? head * HDIM : DMODEL + (head - NHQ) * HDIM);
  u32* p = (u32*)(qkv + base + 2 * i);
  const u32 v = *p;
  const float x0 = bf2f((u16)(v & 0xffffu)), x1 = bf2f((u16)(v >> 16));
  const float ang = (float)s * exp2f(-0.29580575889569023f * (float)i);
  float sn, cs;
  sincosf(ang, &sn, &cs);
  const float y0 = x0 * cs - x1 * sn;
  const float y1 = x0 * sn + x1 * cs;
  *p = (u32)f2bf(y0) | ((u32)f2bf(y1) << 16);
}

// -------------------- Flash attention (causal, GQA) --------------------
__global__ __launch_bounds__(256) void k_attn(const u16* __restrict__ qkv, u16* __restrict__ o){
  const int qb = blockIdx.x, h = blockIdx.y;
  const int kh = h >> 2;                      // GQA: G=4
  const int t = threadIdx.x, w = t >> 6, lane = t & 63, l15 = lane & 15, g = lane >> 4;
  __shared__ u16 Ks[64 * 144];
  __shared__ u16 Vt[128 * 80];
  __shared__ u16 Ps[4][16 * 72];
  const int q0 = qb * 64 + w * 16;
  bf16x8 aq[4];
  #pragma unroll
  for (int d0 = 0; d0 < 4; ++d0)
    aq[d0] = ld8(qkv + (long)(q0 + l15) * NQKV + h * HDIM + d0 * 32 + g * 8);
  f32x4 acc_o[8] = {};
  float mst[4], lst[4];
  #pragma unroll
  for (int r = 0; r < 4; ++r){ mst[r] = -1e30f; lst[r] = 0.f; }
  const float scale = 0.08838834764831843f;
  const int krow = t >> 2, kc0 = (t & 3) << 5;
  const int vkv = (t & 31) << 1, vd0 = (t >> 5) << 4;
  for (int kt = 0; kt <= qb; ++kt){
    const int kv0 = kt << 6;
    __syncthreads();
    {
      const u16* kp = qkv + (long)(kv0 + krow) * NQKV + DMODEL + kh * HDIM + kc0;
      u16* kd = Ks + krow * 144 + kc0;
      #pragma unroll
      for (int c = 0; c < 4; ++c)
        *(uint4*)(kd + c * 8) = *(const uint4*)(kp + c * 8);
    }
    {
      const u16* vp = qkv + (long)(kv0 + vkv) * NQKV + DMODEL + 512 + kh * HDIM + vd0;
      const uint4 a0 = *(const uint4*)vp;
      const uint4 a1 = *(const uint4*)(vp + 8);
      const uint4 b0 = *(const uint4*)(vp + NQKV);
      const uint4 b1 = *(const uint4*)(vp + NQKV + 8);
      const u32 aw[8] = {a0.x,a0.y,a0.z,a0.w,a1.x,a1.y,a1.z,a1.w};
      const u32 bw[8] = {b0.x,b0.y,b0.z,b0.w,b1.x,b1.y,b1.z,b1.w};
      #pragma unroll
      for (int i2 = 0; i2 < 8; ++i2){
        *(u32*)(Vt + (vd0 + 2 * i2)     * 80 + vkv) = (aw[i2] & 0xffffu) | ((bw[i2] & 0xffffu) << 16);
        *(u32*)(Vt + (vd0 + 2 * i2 + 1) * 80 + vkv) = (aw[i2] >> 16)     | ((bw[i2] >> 16) << 16);
      }
    }
    __syncthreads();
    f32x4 sacc[4] = {};
    #pragma unroll
    for (int d0 = 0; d0 < 4; ++d0){
      #pragma unroll
      for (int j = 0; j < 4; ++j){
        const bf16x8 bk = ld8(Ks + (j * 16 + l15) * 144 + d0 * 32 + g * 8);
        sacc[j] = mfma16(aq[d0], bk, sacc[j]);
      }
    }
    float p[4][4], scl[4];
    #pragma unroll
    for (int r = 0; r < 4; ++r){
      const int qrow = q0 + g * 4 + r;
      float mx = -1e30f;
      #pragma unroll
      for (int j = 0; j < 4; ++j){
        float sv = sacc[j][r] * scale;
        sv = (kv0 + j * 16 + l15 <= qrow) ? sv : -1e30f;
        p[j][r] = sv;
        mx = fmaxf(mx, sv);
      }
      #pragma unroll
      for (int off = 1; off < 16; off <<= 1) mx = fmaxf(mx, __shfl_xor(mx, off, 64));
      const float mnew = fmaxf(mst[r], mx);
      scl[r] = __expf(mst[r] - mnew);
      float rs = 0.f;
      #pragma unroll
      for (int j = 0; j < 4; ++j){ p[j][r] = __expf(p[j][r] - mnew); rs += p[j][r]; }
      #pragma unroll
      for (int off = 1; off < 16; off <<= 1) rs += __shfl_xor(rs, off, 64);
      lst[r] = lst[r] * scl[r] + rs;
      mst[r] = mnew;
    }
    #pragma unroll
    for (int n = 0; n < 8; ++n)
      #pragma unroll
      for (int r = 0; r < 4; ++r)
        acc_o[n][r] *= scl[r];
    #pragma unroll
    for (int j = 0; j < 4; ++j)
      #pragma unroll
      for (int r = 0; r < 4; ++r)
        Ps[w][(g * 4 + r) * 72 + j * 16 + l15] = f2bf(p[j][r]);
    #pragma unroll
    for (int kk = 0; kk < 2; ++kk){
      const bf16x8 pa = ld8(Ps[w] + l15 * 72 + kk * 32 + g * 8);
      #pragma unroll
      for (int n = 0; n < 8; ++n){
        const bf16x8 bv = ld8(Vt + (n * 16 + l15) * 80 + kk * 32 + g * 8);
        acc_o[n] = mfma16(pa, bv, acc_o[n]);
      }
    }
  }
  #pragma unroll
  for (int n = 0; n < 8; ++n){
    #pragma unroll
    for (int r = 0; r < 4; ++r){
      const float ov = acc_o[n][r] / lst[r];
      o[(long)(q0 + g * 4 + r) * DMODEL + h * HDIM + n * 16 + l15] = f2bf(ov);
    }
  }
}

// -------------------- SwiGLU: silu(gate)*up --------------------
__global__ void k_swiglu(const u16* __restrict__ gu, u16* __restrict__ out){
  const long idx = ((long)blockIdx.x * 256 + threadIdx.x) * 8;
  const long s = idx >> 13;
  const int j = (int)(idx & 8191);
  const u16* gp = gu + s * 16384 + j;
  const uint4 gv = *(const uint4*)gp;
  const uint4 uv = *(const uint4*)(gp + PDIM);
  const u32 gw[4] = {gv.x, gv.y, gv.z, gv.w};
  const u32 uw[4] = {uv.x, uv.y, uv.z, uv.w};
  u32 ow[4];
  #pragma unroll
  for (int k = 0; k < 4; ++k){
    const float g0 = bf2f((u16)(gw[k] & 0xffffu)), g1 = bf2f((u16)(gw[k] >> 16));
    const float u0 = bf2f((u16)(uw[k] & 0xffffu)), u1 = bf2f((u16)(uw[k] >> 16));
    const float s0 = g0 / (1.f + __expf(-g0)) * u0;
    const float s1 = g1 / (1.f + __expf(-g1)) * u1;
    ow[k] = (u32)f2bf(s0) | ((u32)f2bf(s1) << 16);
  }
  uint4 ro; ro.x = ow[0]; ro.y = ow[1]; ro.z = ow[2]; ro.w = ow[3];
  *(uint4*)(out + idx) = ro;
}

// -------------------- launch --------------------
extern "C" void kernel_launch(void* const* d_in, const int* in_sizes, int n_in,
                              void* d_out, int out_size, void* d_ws, size_t ws_size,
                              hipStream_t stream){
  const int*   tokens       = (const int*)d_in[0];
  const float* embed        = (const float*)d_in[1];
  const float* attn_norm_w  = (const float*)d_in[2];
  const float* qkv_w        = (const float*)d_in[3];
  const float* attn_out_w   = (const float*)d_in[4];
  const float* mlp_norm_w   = (const float*)d_in[5];
  const float* mlp_in_w     = (const float*)d_in[6];
  const float* mlp_out_w    = (const float*)d_in[7];
  const float* final_norm_w = (const float*)d_in[8];
  const float* lm_head_w    = (const float*)d_in[9];

  char* ws = (char*)d_ws;
  float* xf  = (float*)(ws);                    // 16.78 MB residual (fp32)
  u16* hbf   = (u16*)(ws + 16777216);           //  8.39 MB normed activations
  u16* qkvb  = (u16*)(ws + 25165824);           // 12.58 MB qkv
  u16* obf   = (u16*)(ws + 37748736);           //  8.39 MB attn out
  u16* gub   = (u16*)(ws + 46137344);           // 67.11 MB gate|up
  u16* hb2   = (u16*)(ws + 113246208);          // 33.55 MB silu(g)*u
  u16* wbuf  = (u16*)(ws + 146800640);          // 131.07 MB transposed bf16 weights

  k_embed<<<S_LEN, 256, 0, stream>>>(tokens, embed, xf);
  for (int l = 0; l < 2; ++l){
    k_rmsnorm<<<S_LEN, 256, 0, stream>>>(xf, attn_norm_w + (long)l * DMODEL, hbf);
    k_convT<<<dim3(NQKV/64, DMODEL/64), 256, 0, stream>>>(
        qkv_w + (long)l * DMODEL * NQKV, wbuf, NQKV, DMODEL);
    k_gemm<1,0><<<dim3(S_LEN/128, NQKV/128), 256, 0, stream>>>(
        hbf, wbuf, qkvb, nullptr, S_LEN, NQKV, DMODEL);
    k_rope<<<(S_LEN * 20 * 64) / 256, 256, 0, stream>>>(qkvb);
    k_attn<<<dim3(S_LEN/64, NHQ), 256, 0, stream>>>(qkvb, obf);
    k_convT<<<dim3(DMODEL/64, DMODEL/64), 256, 0, stream>>>(
        attn_out_w + (long)l * DMODEL * DMODEL, wbuf, DMODEL, DMODEL);
    k_gemm<0,1><<<dim3(S_LEN/128, DMODEL/128), 256, 0, stream>>>(
        obf, wbuf, xf, xf, S_LEN, DMODEL, DMODEL);
    k_rmsnorm<<<S_LEN, 256, 0, stream>>>(xf, mlp_norm_w + (long)l * DMODEL, hbf);
    k_convT<<<dim3((2*PDIM)/64, DMODEL/64), 256, 0, stream>>>(
        mlp_in_w + (long)l * DMODEL * 2 * PDIM, wbuf, 2*PDIM, DMODEL);
    k_gemm256<1><<<(S_LEN/256) * ((2*PDIM)/256), 512, 0, stream>>>(
        hbf, wbuf, gub, S_LEN, 2*PDIM, DMODEL);
    k_swiglu<<<(S_LEN * PDIM / 8) / 256, 256, 0, stream>>>(gub, hb2);
    k_convT<<<dim3(DMODEL/64, PDIM/64), 256, 0, stream>>>(
        mlp_out_w + (long)l * PDIM * DMODEL, wbuf, DMODEL, PDIM);
    k_gemm<0,1><<<dim3(S_LEN/128, DMODEL/128), 256, 0, stream>>>(
        hb2, wbuf, xf, xf, S_LEN, DMODEL, PDIM);
  }
  k_rmsnorm<<<S_LEN, 256, 0, stream>>>(xf, final_norm_w, hbf);
  k_convT<<<dim3(VOCAB/64, DMODEL/64), 256, 0, stream>>>(lm_head_w, wbuf, VOCAB, DMODEL);
  k_gemm256<0><<<(S_LEN/256) * (VOCAB/256), 512, 0, stream>>>(
      hbf, wbuf, (float*)d_out, S_LEN, VOCAB, DMODEL);
}

// Round 4
// 1601.553 us; speedup vs baseline: 1.6974x; 1.0148x over previous
//
#include <hip/hip_runtime.h>
#include <math.h>

#define S_LEN 2048
#define DMODEL 2048
#define NHQ 16
#define NHK 4
#define HDIM 128
#define PDIM 8192
#define VOCAB 32000
#define NQKV 3072          // D + 2*HK*HD
#define EPSI 1e-5f

typedef unsigned short u16;
typedef unsigned int u32;
typedef __bf16 bf16x8 __attribute__((ext_vector_type(8)));
typedef float f32x4 __attribute__((ext_vector_type(4)));

__device__ __forceinline__ u16 f2bf(float f){
  u32 u = __builtin_bit_cast(u32, f);
  u += 0x7fffu + ((u >> 16) & 1u);   // RNE
  return (u16)(u >> 16);
}
__device__ __forceinline__ float bf2f(u16 h){
  u32 u = ((u32)h) << 16;
  return __builtin_bit_cast(float, u);
}
__device__ __forceinline__ bf16x8 ld8(const u16* p){
  return __builtin_bit_cast(bf16x8, *(const uint4*)p);
}
__device__ __forceinline__ f32x4 mfma16(bf16x8 a, bf16x8 b, f32x4 c){
  return __builtin_amdgcn_mfma_f32_16x16x32_bf16(a, b, c, 0, 0, 0);
}

#define GLOAD_LDS16(gp, lp) __builtin_amdgcn_global_load_lds( \
    (__attribute__((address_space(1))) void*)(gp), \
    (__attribute__((address_space(3))) void*)(lp), 16, 0, 0)

// Swizzled LDS tile layout: [Rows][32] bf16 stored as row-PAIRS; LDS line
// Rp = R>>1 holds rows {2Rp,2Rp+1} x 32 = 128 B = 8 slots of 16 B, slot
// XOR-permuted by (Rp&7). gload_lds dest LINEAR; permutation applied to the
// per-lane GLOBAL source address (involution both sides). Frag reads: 0 bank
// conflicts measured (R3).
__device__ __forceinline__ bf16x8 lds_frag(const u16* Lb, int R, int g){
  const int Rp = R >> 1;
  const int s8 = (((R & 1) << 2) | g) ^ (Rp & 7);
  return ld8(Lb + Rp * 64 + s8 * 8);
}
__device__ __forceinline__ void stage_sw(const u16* base, long row0, int K, int kt,
                                         int q, u16* Ldst_waveuniform){
  const int Rp = q >> 3;
  const int u = (q & 7) ^ (Rp & 7);
  const int R = (Rp << 1) | (u >> 2);
  const u16* gp = base + (row0 + R) * (long)K + kt + ((u & 3) << 3);
  GLOAD_LDS16(gp, Ldst_waveuniform);
}

// -------------------- embed gather --------------------
__global__ void k_embed(const int* __restrict__ tok, const float* __restrict__ emb,
                        float* __restrict__ x){
  const int s = blockIdx.x, t = threadIdx.x;
  const long r = tok[s];
  const float4* src = (const float4*)(emb + r * DMODEL);
  float4* dst = (float4*)(x + (long)s * DMODEL);
  dst[t] = src[t];
  dst[t + 256] = src[t + 256];
}

// -------------------- RMSNorm: fp32 in -> bf16 out --------------------
__global__ void k_rmsnorm(const float* __restrict__ x, const float* __restrict__ w,
                          u16* __restrict__ out){
  const int s = blockIdx.x, t = threadIdx.x;
  const float4* xr = (const float4*)(x + (long)s * DMODEL);
  const float4 a = xr[t], b = xr[t + 256];
  float ss = a.x*a.x + a.y*a.y + a.z*a.z + a.w*a.w
           + b.x*b.x + b.y*b.y + b.z*b.z + b.w*b.w;
  #pragma unroll
  for (int off = 32; off > 0; off >>= 1) ss += __shfl_down(ss, off, 64);
  __shared__ float part[4];
  if ((t & 63) == 0) part[t >> 6] = ss;
  __syncthreads();
  const float r = rsqrtf((part[0] + part[1] + part[2] + part[3]) * (1.f / 2048.f) + EPSI);
  const float4* wr = (const float4*)w;
  const float4 wa = wr[t], wb = wr[t + 256];
  uint2 ua, ub;
  ua.x = (u32)f2bf(a.x*r*wa.x) | ((u32)f2bf(a.y*r*wa.y) << 16);
  ua.y = (u32)f2bf(a.z*r*wa.z) | ((u32)f2bf(a.w*r*wa.w) << 16);
  ub.x = (u32)f2bf(b.x*r*wb.x) | ((u32)f2bf(b.y*r*wb.y) << 16);
  ub.y = (u32)f2bf(b.z*r*wb.z) | ((u32)f2bf(b.w*r*wb.w) << 16);
  *(uint2*)(out + (long)s * DMODEL + 4 * t) = ua;
  *(uint2*)(out + (long)s * DMODEL + 1024 + 4 * t) = ub;
}

// -------------------- weight convert + transpose: W f32[K][N] -> Wt bf16[N][K] ---
__global__ __launch_bounds__(256) void k_convT(const float* __restrict__ W,
                                               u16* __restrict__ Wt, int N, int K){
  const int n0 = blockIdx.x * 64, k0 = blockIdx.y * 64;
  const int t = threadIdx.x;
  __shared__ u16 T[64][72];    // [n][k], padded
  const int r = t >> 4, c = (t & 15) << 2;
  #pragma unroll
  for (int p = 0; p < 4; ++p){
    const int k = p * 16 + r;
    const float4 v = *(const float4*)(W + (long)(k0 + k) * N + n0 + c);
    T[c + 0][k] = f2bf(v.x);
    T[c + 1][k] = f2bf(v.y);
    T[c + 2][k] = f2bf(v.z);
    T[c + 3][k] = f2bf(v.w);
  }
  __syncthreads();
  const int nr = t >> 3, kc = (t & 7) << 3;
  #pragma unroll
  for (int p = 0; p < 2; ++p){
    const int n = p * 32 + nr;
    *(uint4*)(Wt + (long)(n0 + n) * K + k0 + kc) = *(const uint4*)(&T[n][kc]);
  }
}

// -------------------- GEMM 128x128 (m97-structure, swizzled LDS) --------------------
template<int OUT_BF16, int RES>
__global__ __launch_bounds__(256) void k_gemm(const u16* __restrict__ A, const u16* __restrict__ Bt,
                                              void* C, const float* Rs,
                                              int M, int N, int K){
  const int bm = blockIdx.x, bn = blockIdx.y;
  const int t = threadIdx.x;
  const int w = t >> 6, lane = t & 63, l15 = lane & 15, g = lane >> 4;
  const int wr = w >> 1, wc = w & 1;
  __shared__ u16 As[4096];
  __shared__ u16 Bs[4096];
  f32x4 acc[4][4] = {};
  const long arow = (long)bm * 128;
  const long brow = (long)bn * 128;
  for (int kt = 0; kt < K; kt += 32){
    __syncthreads();
    #pragma unroll
    for (int c = 0; c < 2; ++c){
      const int q0 = ((w << 1) | c) << 6;
      const int q  = q0 | lane;
      stage_sw(A,  arow, K, kt, q, As + q0 * 8);
      stage_sw(Bt, brow, K, kt, q, Bs + q0 * 8);
    }
    __syncthreads();
    bf16x8 af[4], bfr[4];
    #pragma unroll
    for (int i = 0; i < 4; ++i)
      af[i] = lds_frag(As, wr * 64 + i * 16 + l15, g);
    #pragma unroll
    for (int i = 0; i < 4; ++i)
      bfr[i] = lds_frag(Bs, wc * 64 + i * 16 + l15, g);
    #pragma unroll
    for (int mi = 0; mi < 4; ++mi)
      #pragma unroll
      for (int ni = 0; ni < 4; ++ni)
        acc[mi][ni] = mfma16(af[mi], bfr[ni], acc[mi][ni]);
  }
  const int row0 = bm * 128 + wr * 64, col0 = bn * 128 + wc * 64;
  #pragma unroll
  for (int mi = 0; mi < 4; ++mi){
    #pragma unroll
    for (int ni = 0; ni < 4; ++ni){
      #pragma unroll
      for (int r = 0; r < 4; ++r){
        const long ri = row0 + mi * 16 + g * 4 + r;
        const long ci = col0 + ni * 16 + l15;
        float v = acc[mi][ni][r];
        if (RES) v += Rs[ri * N + ci];
        if (OUT_BF16) ((u16*)C)[ri * N + ci] = f2bf(v);
        else          ((float*)C)[ri * N + ci] = v;
      }
    }
  }
}

// -------------------- GEMM 256x256, 8 waves, 4-deep, single fat phase/K-tile ----
// BK=32, 4 LDS slots (A+B = 32 KB each) = 128 KB. Per K-tile: 12 ds_read_b128
// (all frags) + 4 gload_lds (hoisted pointers, +64B/tile) + lgkmcnt(0) +
// vmcnt(8) + 1 barrier + 32-MFMA burst under setprio. Gate math: stages for
// tiles tt+1..tt+3 in flight = 12 loads; vmcnt(8) => tile tt+1 landed.
// WAR: reads drained (lgkmcnt 0) before each barrier; DMA for tile tt+3
// issued after that barrier, targets buffer whose reads drained previously.
template<int OUT_BF16>
__global__ __launch_bounds__(512, 2) void k_gemm256(const u16* __restrict__ A,
                                                    const u16* __restrict__ Bt,
                                                    void* C, int M, int N, int K){
  __shared__ u16 L[65536];                   // 128 KB: A slots [0,32768), B at +32768
  const int t = threadIdx.x;
  const int w = t >> 6, lane = t & 63, l15 = lane & 15, g = lane >> 4;
  const int wr = w >> 2, wc = w & 3;         // 2M x 4N waves; per-wave out 128x64
  const int nbm = M >> 8;
  int id = blockIdx.x;
  {
    const int cpx = gridDim.x >> 3;          // nwg % 8 == 0 at all call sites
    id = (id & 7) * cpx + (id >> 3);
  }
  const int bm = id % nbm, bn = id / nbm;
  const int NT = K >> 5;

  // hoisted staging addresses: thread's chunk q=t (and q+512 = +128 rows)
  const int Rp0 = t >> 3;
  const int u0  = (t & 7) ^ (Rp0 & 7);
  const int R0  = (Rp0 << 1) | (u0 >> 2);
  const u16* pA0 = A  + ((long)bm * 256 + R0) * (long)K + ((u0 & 3) << 3);
  const u16* pB0 = Bt + ((long)bn * 256 + R0) * (long)K + ((u0 & 3) << 3);
  const u16* pA1 = pA0 + (long)128 * K;
  const u16* pB1 = pB0 + (long)128 * K;
  const int w0 = (t & ~63) * 8;              // wave-uniform LDS chunk base (u16)

  auto stagef = [&](int slot){
    u16* ldsA = L + slot * 8192;
    u16* ldsB = L + 32768 + slot * 8192;
    GLOAD_LDS16(pA0, ldsA + w0);
    GLOAD_LDS16(pB0, ldsB + w0);
    GLOAD_LDS16(pA1, ldsA + 4096 + w0);
    GLOAD_LDS16(pB1, ldsB + 4096 + w0);
    pA0 += 32; pB0 += 32; pA1 += 32; pB1 += 32;
  };

  stagef(0); stagef(1); stagef(2);
  asm volatile("s_waitcnt vmcnt(8)" ::: "memory");
  __builtin_amdgcn_s_barrier();

  f32x4 acc[8][4] = {};
  for (int tt = 0; tt < NT; ++tt){
    const u16* sA = L + (tt & 3) * 8192;
    const u16* sB = L + 32768 + (tt & 3) * 8192;
    bf16x8 af[8], bfr[4];
    #pragma unroll
    for (int j = 0; j < 8; ++j)
      af[j] = lds_frag(sA, wr * 128 + j * 16 + l15, g);
    #pragma unroll
    for (int n = 0; n < 4; ++n)
      bfr[n] = lds_frag(sB, wc * 64 + n * 16 + l15, g);
    if (tt + 3 < NT) stagef((tt + 3) & 3);
    if (tt + 1 < NT){
      asm volatile("s_waitcnt lgkmcnt(0)" ::: "memory");   // drain reads pre-barrier (WAR)
      if (tt + 3 < NT)      asm volatile("s_waitcnt vmcnt(8)" ::: "memory");
      else if (tt + 2 < NT) asm volatile("s_waitcnt vmcnt(4)" ::: "memory");
      else                  asm volatile("s_waitcnt vmcnt(0)" ::: "memory");
      __builtin_amdgcn_s_barrier();
    }
    __builtin_amdgcn_s_setprio(1);
    #pragma unroll
    for (int mi = 0; mi < 8; ++mi)
      #pragma unroll
      for (int ni = 0; ni < 4; ++ni)
        acc[mi][ni] = mfma16(af[mi], bfr[ni], acc[mi][ni]);
    __builtin_amdgcn_s_setprio(0);
  }
  // ---- epilogue ----
  const int row0 = bm * 256 + wr * 128, col0 = bn * 256 + wc * 64;
  #pragma unroll
  for (int mi = 0; mi < 8; ++mi){
    #pragma unroll
    for (int ni = 0; ni < 4; ++ni){
      #pragma unroll
      for (int r = 0; r < 4; ++r){
        const long ri = row0 + mi * 16 + g * 4 + r;
        const long ci = col0 + ni * 16 + l15;
        const float v = acc[mi][ni][r];
        if (OUT_BF16) ((u16*)C)[ri * N + ci] = f2bf(v);
        else          ((float*)C)[ri * N + ci] = v;
      }
    }
  }
}

// -------------------- RoPE in-place on bf16 qkv --------------------
__global__ void k_rope(u16* __restrict__ qkv){
  const int idx = blockIdx.x * 256 + threadIdx.x;   // S * 20 * 64
  const int i = idx & 63;
  const int head = (idx >> 6) % 20;
  const int s = idx / (64 * 20);
  const long base = (long)s * NQKV + (head < NHQ ? head * HDIM : DMODEL + (head - NHQ) * HDIM);
  u32* p = (u32*)(qkv + base + 2 * i);
  const u32 v = *p;
  const float x0 = bf2f((u16)(v & 0xffffu)), x1 = bf2f((u16)(v >> 16));
  const float ang = (float)s * exp2f(-0.29580575889569023f * (float)i);
  float sn, cs;
  sincosf(ang, &sn, &cs);
  const float y0 = x0 * cs - x1 * sn;
  const float y1 = x0 * sn + x1 * cs;
  *p = (u32)f2bf(y0) | ((u32)f2bf(y1) << 16);
}

// -------------------- Flash attention (causal, GQA) --------------------
__global__ __launch_bounds__(256) void k_attn(const u16* __restrict__ qkv, u16* __restrict__ o){
  const int qb = blockIdx.x, h = blockIdx.y;
  const int kh = h >> 2;                      // GQA: G=4
  const int t = threadIdx.x, w = t >> 6, lane = t & 63, l15 = lane & 15, g = lane >> 4;
  __shared__ u16 Ks[64 * 144];
  __shared__ u16 Vt[128 * 80];
  __shared__ u16 Ps[4][16 * 72];
  const int q0 = qb * 64 + w * 16;
  bf16x8 aq[4];
  #pragma unroll
  for (int d0 = 0; d0 < 4; ++d0)
    aq[d0] = ld8(qkv + (long)(q0 + l15) * NQKV + h * HDIM + d0 * 32 + g * 8);
  f32x4 acc_o[8] = {};
  float mst[4], lst[4];
  #pragma unroll
  for (int r = 0; r < 4; ++r){ mst[r] = -1e30f; lst[r] = 0.f; }
  const float scale = 0.08838834764831843f;
  const int krow = t >> 2, kc0 = (t & 3) << 5;
  const int vkv = (t & 31) << 1, vd0 = (t >> 5) << 4;
  for (int kt = 0; kt <= qb; ++kt){
    const int kv0 = kt << 6;
    __syncthreads();
    {
      const u16* kp = qkv + (long)(kv0 + krow) * NQKV + DMODEL + kh * HDIM + kc0;
      u16* kd = Ks + krow * 144 + kc0;
      #pragma unroll
      for (int c = 0; c < 4; ++c)
        *(uint4*)(kd + c * 8) = *(const uint4*)(kp + c * 8);
    }
    {
      const u16* vp = qkv + (long)(kv0 + vkv) * NQKV + DMODEL + 512 + kh * HDIM + vd0;
      const uint4 a0 = *(const uint4*)vp;
      const uint4 a1 = *(const uint4*)(vp + 8);
      const uint4 b0 = *(const uint4*)(vp + NQKV);
      const uint4 b1 = *(const uint4*)(vp + NQKV + 8);
      const u32 aw[8] = {a0.x,a0.y,a0.z,a0.w,a1.x,a1.y,a1.z,a1.w};
      const u32 bw[8] = {b0.x,b0.y,b0.z,b0.w,b1.x,b1.y,b1.z,b1.w};
      #pragma unroll
      for (int i2 = 0; i2 < 8; ++i2){
        *(u32*)(Vt + (vd0 + 2 * i2)     * 80 + vkv) = (aw[i2] & 0xffffu) | ((bw[i2] & 0xffffu) << 16);
        *(u32*)(Vt + (vd0 + 2 * i2 + 1) * 80 + vkv) = (aw[i2] >> 16)     | ((bw[i2] >> 16) << 16);
      }
    }
    __syncthreads();
    f32x4 sacc[4] = {};
    #pragma unroll
    for (int d0 = 0; d0 < 4; ++d0){
      #pragma unroll
      for (int j = 0; j < 4; ++j){
        const bf16x8 bk = ld8(Ks + (j * 16 + l15) * 144 + d0 * 32 + g * 8);
        sacc[j] = mfma16(aq[d0], bk, sacc[j]);
      }
    }
    float p[4][4], scl[4];
    #pragma unroll
    for (int r = 0; r < 4; ++r){
      const int qrow = q0 + g * 4 + r;
      float mx = -1e30f;
      #pragma unroll
      for (int j = 0; j < 4; ++j){
        float sv = sacc[j][r] * scale;
        sv = (kv0 + j * 16 + l15 <= qrow) ? sv : -1e30f;
        p[j][r] = sv;
        mx = fmaxf(mx, sv);
      }
      #pragma unroll
      for (int off = 1; off < 16; off <<= 1) mx = fmaxf(mx, __shfl_xor(mx, off, 64));
      const float mnew = fmaxf(mst[r], mx);
      scl[r] = __expf(mst[r] - mnew);
      float rs = 0.f;
      #pragma unroll
      for (int j = 0; j < 4; ++j){ p[j][r] = __expf(p[j][r] - mnew); rs += p[j][r]; }
      #pragma unroll
      for (int off = 1; off < 16; off <<= 1) rs += __shfl_xor(rs, off, 64);
      lst[r] = lst[r] * scl[r] + rs;
      mst[r] = mnew;
    }
    #pragma unroll
    for (int n = 0; n < 8; ++n)
      #pragma unroll
      for (int r = 0; r < 4; ++r)
        acc_o[n][r] *= scl[r];
    #pragma unroll
    for (int j = 0; j < 4; ++j)
      #pragma unroll
      for (int r = 0; r < 4; ++r)
        Ps[w][(g * 4 + r) * 72 + j * 16 + l15] = f2bf(p[j][r]);
    #pragma unroll
    for (int kk = 0; kk < 2; ++kk){
      const bf16x8 pa = ld8(Ps[w] + l15 * 72 + kk * 32 + g * 8);
      #pragma unroll
      for (int n = 0; n < 8; ++n){
        const bf16x8 bv = ld8(Vt + (n * 16 + l15) * 80 + kk * 32 + g * 8);
        acc_o[n] = mfma16(pa, bv, acc_o[n]);
      }
    }
  }
  #pragma unroll
  for (int n = 0; n < 8; ++n){
    #pragma unroll
    for (int r = 0; r < 4; ++r){
      const float ov = acc_o[n][r] / lst[r];
      o[(long)(q0 + g * 4 + r) * DMODEL + h * HDIM + n * 16 + l15] = f2bf(ov);
    }
  }
}

// -------------------- SwiGLU: silu(gate)*up --------------------
__global__ void k_swiglu(const u16* __restrict__ gu, u16* __restrict__ out){
  const long idx = ((long)blockIdx.x * 256 + threadIdx.x) * 8;
  const long s = idx >> 13;
  const int j = (int)(idx & 8191);
  const u16* gp = gu + s * 16384 + j;
  const uint4 gv = *(const uint4*)gp;
  const uint4 uv = *(const uint4*)(gp + PDIM);
  const u32 gw[4] = {gv.x, gv.y, gv.z, gv.w};
  const u32 uw[4] = {uv.x, uv.y, uv.z, uv.w};
  u32 ow[4];
  #pragma unroll
  for (int k = 0; k < 4; ++k){
    const float g0 = bf2f((u16)(gw[k] & 0xffffu)), g1 = bf2f((u16)(gw[k] >> 16));
    const float u0 = bf2f((u16)(uw[k] & 0xffffu)), u1 = bf2f((u16)(uw[k] >> 16));
    const float s0 = g0 / (1.f + __expf(-g0)) * u0;
    const float s1 = g1 / (1.f + __expf(-g1)) * u1;
    ow[k] = (u32)f2bf(s0) | ((u32)f2bf(s1) << 16);
  }
  uint4 ro; ro.x = ow[0]; ro.y = ow[1]; ro.z = ow[2]; ro.w = ow[3];
  *(uint4*)(out + idx) = ro;
}

// -------------------- launch --------------------
extern "C" void kernel_launch(void* const* d_in, const int* in_sizes, int n_in,
                              void* d_out, int out_size, void* d_ws, size_t ws_size,
                              hipStream_t stream){
  const int*   tokens       = (const int*)d_in[0];
  const float* embed        = (const float*)d_in[1];
  const float* attn_norm_w  = (const float*)d_in[2];
  const float* qkv_w        = (const float*)d_in[3];
  const float* attn_out_w   = (const float*)d_in[4];
  const float* mlp_norm_w   = (const float*)d_in[5];
  const float* mlp_in_w     = (const float*)d_in[6];
  const float* mlp_out_w    = (const float*)d_in[7];
  const float* final_norm_w = (const float*)d_in[8];
  const float* lm_head_w    = (const float*)d_in[9];

  char* ws = (char*)d_ws;
  float* xf  = (float*)(ws);                    // 16.78 MB residual (fp32)
  u16* hbf   = (u16*)(ws + 16777216);           //  8.39 MB normed activations
  u16* qkvb  = (u16*)(ws + 25165824);           // 12.58 MB qkv
  u16* obf   = (u16*)(ws + 37748736);           //  8.39 MB attn out
  u16* gub   = (u16*)(ws + 46137344);           // 67.11 MB gate|up
  u16* hb2   = (u16*)(ws + 113246208);          // 33.55 MB silu(g)*u
  u16* wbuf  = (u16*)(ws + 146800640);          // 131.07 MB transposed bf16 weights

  k_embed<<<S_LEN, 256, 0, stream>>>(tokens, embed, xf);
  for (int l = 0; l < 2; ++l){
    k_rmsnorm<<<S_LEN, 256, 0, stream>>>(xf, attn_norm_w + (long)l * DMODEL, hbf);
    k_convT<<<dim3(NQKV/64, DMODEL/64), 256, 0, stream>>>(
        qkv_w + (long)l * DMODEL * NQKV, wbuf, NQKV, DMODEL);
    k_gemm<1,0><<<dim3(S_LEN/128, NQKV/128), 256, 0, stream>>>(
        hbf, wbuf, qkvb, nullptr, S_LEN, NQKV, DMODEL);
    k_rope<<<(S_LEN * 20 * 64) / 256, 256, 0, stream>>>(qkvb);
    k_attn<<<dim3(S_LEN/64, NHQ), 256, 0, stream>>>(qkvb, obf);
    k_convT<<<dim3(DMODEL/64, DMODEL/64), 256, 0, stream>>>(
        attn_out_w + (long)l * DMODEL * DMODEL, wbuf, DMODEL, DMODEL);
    k_gemm<0,1><<<dim3(S_LEN/128, DMODEL/128), 256, 0, stream>>>(
        obf, wbuf, xf, xf, S_LEN, DMODEL, DMODEL);
    k_rmsnorm<<<S_LEN, 256, 0, stream>>>(xf, mlp_norm_w + (long)l * DMODEL, hbf);
    k_convT<<<dim3((2*PDIM)/64, DMODEL/64), 256, 0, stream>>>(
        mlp_in_w + (long)l * DMODEL * 2 * PDIM, wbuf, 2*PDIM, DMODEL);
    k_gemm256<1><<<(S_LEN/256) * ((2*PDIM)/256), 512, 0, stream>>>(
        hbf, wbuf, gub, S_LEN, 2*PDIM, DMODEL);
    k_swiglu<<<(S_LEN * PDIM / 8) / 256, 256, 0, stream>>>(gub, hb2);
    k_convT<<<dim3(DMODEL/64, PDIM/64), 256, 0, stream>>>(
        mlp_out_w + (long)l * PDIM * DMODEL, wbuf, DMODEL, PDIM);
    k_gemm<0,1><<<dim3(S_LEN/128, DMODEL/128), 256, 0, stream>>>(
        hb2, wbuf, xf, xf, S_LEN, DMODEL, PDIM);
  }
  k_rmsnorm<<<S_LEN, 256, 0, stream>>>(xf, final_norm_w, hbf);
  k_convT<<<dim3(VOCAB/64, DMODEL/64), 256, 0, stream>>>(lm_head_w, wbuf, VOCAB, DMODEL);
  k_gemm256<0><<<(S_LEN/256) * (VOCAB/256), 512, 0, stream>>>(
      hbf, wbuf, (float*)d_out, S_LEN, VOCAB, DMODEL);
}

// Round 5
// 1535.279 us; speedup vs baseline: 1.7707x; 1.0432x over previous
//
#include <hip/hip_runtime.h>
#include <math.h>

#define S_LEN 2048
#define DMODEL 2048
#define NHQ 16
#define NHK 4
#define HDIM 128
#define PDIM 8192
#define VOCAB 32000
#define NQKV 3072          // D + 2*HK*HD
#define EPSI 1e-5f

typedef unsigned short u16;
typedef unsigned int u32;
typedef __bf16 bf16x8 __attribute__((ext_vector_type(8)));
typedef float f32x4 __attribute__((ext_vector_type(4)));

__device__ __forceinline__ u16 f2bf(float f){
  u32 u = __builtin_bit_cast(u32, f);
  u += 0x7fffu + ((u >> 16) & 1u);   // RNE
  return (u16)(u >> 16);
}
__device__ __forceinline__ float bf2f(u16 h){
  u32 u = ((u32)h) << 16;
  return __builtin_bit_cast(float, u);
}
__device__ __forceinline__ bf16x8 ld8(const u16* p){
  return __builtin_bit_cast(bf16x8, *(const uint4*)p);
}
__device__ __forceinline__ f32x4 mfma16(bf16x8 a, bf16x8 b, f32x4 c){
  return __builtin_amdgcn_mfma_f32_16x16x32_bf16(a, b, c, 0, 0, 0);
}

#define GLOAD_LDS16(gp, lp) __builtin_amdgcn_global_load_lds( \
    (__attribute__((address_space(1))) void*)(gp), \
    (__attribute__((address_space(3))) void*)(lp), 16, 0, 0)

// Swizzled LDS tile layout (GEMM): [Rows][32] bf16 stored as row-PAIRS; line
// Rp = R>>1 holds rows {2Rp,2Rp+1} x 32 k = 128 B = 8 slots of 16 B, slot
// XOR-permuted by (Rp&7). gload_lds dest LINEAR; permutation applied to the
// per-lane GLOBAL source address. 0 bank conflicts measured (R3/R4).
__device__ __forceinline__ bf16x8 lds_frag(const u16* Lb, int R, int g){
  const int Rp = R >> 1;
  const int s8 = (((R & 1) << 2) | g) ^ (Rp & 7);
  return ld8(Lb + Rp * 64 + s8 * 8);
}
__device__ __forceinline__ void stage_sw(const u16* base, long row0, int K, int kt,
                                         int q, u16* Ldst_waveuniform){
  const int Rp = q >> 3;
  const int u = (q & 7) ^ (Rp & 7);
  const int R = (Rp << 1) | (u >> 2);
  const u16* gp = base + (row0 + R) * (long)K + kt + ((u & 3) << 3);
  GLOAD_LDS16(gp, Ldst_waveuniform);
}

// -------------------- embed gather --------------------
__global__ void k_embed(const int* __restrict__ tok, const float* __restrict__ emb,
                        float* __restrict__ x){
  const int s = blockIdx.x, t = threadIdx.x;
  const long r = tok[s];
  const float4* src = (const float4*)(emb + r * DMODEL);
  float4* dst = (float4*)(x + (long)s * DMODEL);
  dst[t] = src[t];
  dst[t + 256] = src[t + 256];
}

// -------------------- RMSNorm: fp32 in -> bf16 out --------------------
__global__ void k_rmsnorm(const float* __restrict__ x, const float* __restrict__ w,
                          u16* __restrict__ out){
  const int s = blockIdx.x, t = threadIdx.x;
  const float4* xr = (const float4*)(x + (long)s * DMODEL);
  const float4 a = xr[t], b = xr[t + 256];
  float ss = a.x*a.x + a.y*a.y + a.z*a.z + a.w*a.w
           + b.x*b.x + b.y*b.y + b.z*b.z + b.w*b.w;
  #pragma unroll
  for (int off = 32; off > 0; off >>= 1) ss += __shfl_down(ss, off, 64);
  __shared__ float part[4];
  if ((t & 63) == 0) part[t >> 6] = ss;
  __syncthreads();
  const float r = rsqrtf((part[0] + part[1] + part[2] + part[3]) * (1.f / 2048.f) + EPSI);
  const float4* wr = (const float4*)w;
  const float4 wa = wr[t], wb = wr[t + 256];
  uint2 ua, ub;
  ua.x = (u32)f2bf(a.x*r*wa.x) | ((u32)f2bf(a.y*r*wa.y) << 16);
  ua.y = (u32)f2bf(a.z*r*wa.z) | ((u32)f2bf(a.w*r*wa.w) << 16);
  ub.x = (u32)f2bf(b.x*r*wb.x) | ((u32)f2bf(b.y*r*wb.y) << 16);
  ub.y = (u32)f2bf(b.z*r*wb.z) | ((u32)f2bf(b.w*r*wb.w) << 16);
  *(uint2*)(out + (long)s * DMODEL + 4 * t) = ua;
  *(uint2*)(out + (long)s * DMODEL + 1024 + 4 * t) = ub;
}

// -------------------- weight convert + transpose: W f32[K][N] -> Wt bf16[N][K] ---
__global__ __launch_bounds__(256) void k_convT(const float* __restrict__ W,
                                               u16* __restrict__ Wt, int N, int K){
  const int n0 = blockIdx.x * 64, k0 = blockIdx.y * 64;
  const int t = threadIdx.x;
  __shared__ u16 T[64][72];    // [n][k], padded
  const int r = t >> 4, c = (t & 15) << 2;
  #pragma unroll
  for (int p = 0; p < 4; ++p){
    const int k = p * 16 + r;
    const float4 v = *(const float4*)(W + (long)(k0 + k) * N + n0 + c);
    T[c + 0][k] = f2bf(v.x);
    T[c + 1][k] = f2bf(v.y);
    T[c + 2][k] = f2bf(v.z);
    T[c + 3][k] = f2bf(v.w);
  }
  __syncthreads();
  const int nr = t >> 3, kc = (t & 7) << 3;
  #pragma unroll
  for (int p = 0; p < 2; ++p){
    const int n = p * 32 + nr;
    *(uint4*)(Wt + (long)(n0 + n) * K + k0 + kc) = *(const uint4*)(&T[n][kc]);
  }
}

// -------------------- V transpose: qkv V-part [S][4][128] -> vT [4][128][S] ------
__global__ __launch_bounds__(256) void k_transV(const u16* __restrict__ qkv,
                                                u16* __restrict__ vT){
  const int s0 = blockIdx.x * 64, d0 = blockIdx.y * 64, kh = blockIdx.z;
  const int t = threadIdx.x;
  __shared__ u16 T[64][72];   // [d][s]
  #pragma unroll
  for (int p = 0; p < 4; ++p){
    const int s = p * 16 + (t >> 4);
    const int c = (t & 15) * 4;
    const uint2 v = *(const uint2*)(qkv + (long)(s0 + s) * NQKV + DMODEL + 512 + kh * HDIM + d0 + c);
    T[c + 0][s] = (u16)(v.x);
    T[c + 1][s] = (u16)(v.x >> 16);
    T[c + 2][s] = (u16)(v.y);
    T[c + 3][s] = (u16)(v.y >> 16);
  }
  __syncthreads();
  #pragma unroll
  for (int p = 0; p < 2; ++p){
    const int d = p * 32 + (t >> 3);
    *(uint4*)(vT + ((long)kh * HDIM + d0 + d) * S_LEN + s0 + (t & 7) * 8) =
        *(const uint4*)(&T[d][(t & 7) * 8]);
  }
}

// -------------------- GEMM 128x128 (m97-structure, swizzled LDS) --------------------
template<int OUT_BF16, int RES>
__global__ __launch_bounds__(256) void k_gemm(const u16* __restrict__ A, const u16* __restrict__ Bt,
                                              void* C, const float* Rs,
                                              int M, int N, int K){
  const int bm = blockIdx.x, bn = blockIdx.y;
  const int t = threadIdx.x;
  const int w = t >> 6, lane = t & 63, l15 = lane & 15, g = lane >> 4;
  const int wr = w >> 1, wc = w & 1;
  __shared__ u16 As[4096];
  __shared__ u16 Bs[4096];
  f32x4 acc[4][4] = {};
  const long arow = (long)bm * 128;
  const long brow = (long)bn * 128;
  for (int kt = 0; kt < K; kt += 32){
    __syncthreads();
    #pragma unroll
    for (int c = 0; c < 2; ++c){
      const int q0 = ((w << 1) | c) << 6;
      const int q  = q0 | lane;
      stage_sw(A,  arow, K, kt, q, As + q0 * 8);
      stage_sw(Bt, brow, K, kt, q, Bs + q0 * 8);
    }
    __syncthreads();
    bf16x8 af[4], bfr[4];
    #pragma unroll
    for (int i = 0; i < 4; ++i)
      af[i] = lds_frag(As, wr * 64 + i * 16 + l15, g);
    #pragma unroll
    for (int i = 0; i < 4; ++i)
      bfr[i] = lds_frag(Bs, wc * 64 + i * 16 + l15, g);
    #pragma unroll
    for (int mi = 0; mi < 4; ++mi)
      #pragma unroll
      for (int ni = 0; ni < 4; ++ni)
        acc[mi][ni] = mfma16(af[mi], bfr[ni], acc[mi][ni]);
  }
  const int row0 = bm * 128 + wr * 64, col0 = bn * 128 + wc * 64;
  #pragma unroll
  for (int mi = 0; mi < 4; ++mi){
    #pragma unroll
    for (int ni = 0; ni < 4; ++ni){
      #pragma unroll
      for (int r = 0; r < 4; ++r){
        const long ri = row0 + mi * 16 + g * 4 + r;
        const long ci = col0 + ni * 16 + l15;
        float v = acc[mi][ni][r];
        if (RES) v += Rs[ri * N + ci];
        if (OUT_BF16) ((u16*)C)[ri * N + ci] = f2bf(v);
        else          ((float*)C)[ri * N + ci] = v;
      }
    }
  }
}

// -------------------- GEMM 256x256, 8 waves, 4-deep, 2 phases/K-tile --------------
// Per phase: {ds_reads + 2 gload_lds + lgkmcnt(0) [+ counted vmcnt at ph1] +
// barrier + 16-MFMA setprio cluster}. WAR: slot tt-1's A last read ph1(tt-1)
// (drained lgkmcnt+barrier) before ph0(tt) A-DMA; B symmetric at ph0/ph1.
template<int OUT_BF16>
__global__ __launch_bounds__(512, 2) void k_gemm256(const u16* __restrict__ A,
                                                    const u16* __restrict__ Bt,
                                                    void* C, int M, int N, int K){
  __shared__ u16 L[65536];                   // 128 KB: A slots [0,32768), B at +32768
  const int t = threadIdx.x;
  const int w = t >> 6, lane = t & 63, l15 = lane & 15, g = lane >> 4;
  const int wr = w >> 2, wc = w & 3;         // 2M x 4N waves; per-wave out 128x64
  const int nbm = M >> 8;
  int id = blockIdx.x;
  {
    const int cpx = gridDim.x >> 3;          // nwg % 8 == 0 at all call sites
    id = (id & 7) * cpx + (id >> 3);
  }
  const int bm = id % nbm, bn = id / nbm;
  const int NT = K >> 5;

  // hoisted staging addresses: thread's chunk q=t (and q+512 = +128 rows)
  const int Rp0 = t >> 3;
  const int u0  = (t & 7) ^ (Rp0 & 7);
  const int R0  = (Rp0 << 1) | (u0 >> 2);
  const u16* pA0 = A  + ((long)bm * 256 + R0) * (long)K + ((u0 & 3) << 3);
  const u16* pB0 = Bt + ((long)bn * 256 + R0) * (long)K + ((u0 & 3) << 3);
  const u16* pA1 = pA0 + (long)128 * K;
  const u16* pB1 = pB0 + (long)128 * K;
  const int w0 = (t & ~63) * 8;              // wave-uniform LDS chunk base (u16)

  auto stageA = [&](int slot){
    u16* ldsA = L + slot * 8192;
    GLOAD_LDS16(pA0, ldsA + w0);
    GLOAD_LDS16(pA1, ldsA + 4096 + w0);
    pA0 += 32; pA1 += 32;
  };
  auto stageB = [&](int slot){
    u16* ldsB = L + 32768 + slot * 8192;
    GLOAD_LDS16(pB0, ldsB + w0);
    GLOAD_LDS16(pB1, ldsB + 4096 + w0);
    pB0 += 32; pB1 += 32;
  };

  #pragma unroll
  for (int i = 0; i < 3; ++i){ stageA(i); stageB(i); }
  asm volatile("s_waitcnt vmcnt(8)" ::: "memory");
  __builtin_amdgcn_s_barrier();

  f32x4 acc[8][4] = {};
  for (int tt = 0; tt < NT; ++tt){
    const u16* sA = L + (tt & 3) * 8192;
    const u16* sB = L + 32768 + (tt & 3) * 8192;
    // ---- phase 0: m-half 0 ----
    bf16x8 af0[4], bfr[4];
    #pragma unroll
    for (int j = 0; j < 4; ++j)
      af0[j] = lds_frag(sA, wr * 128 + j * 16 + l15, g);
    #pragma unroll
    for (int n = 0; n < 4; ++n)
      bfr[n] = lds_frag(sB, wc * 64 + n * 16 + l15, g);
    if (tt + 3 < NT) stageA((tt + 3) & 3);
    asm volatile("s_waitcnt lgkmcnt(0)" ::: "memory");
    __builtin_amdgcn_s_barrier();
    __builtin_amdgcn_s_setprio(1);
    #pragma unroll
    for (int mi = 0; mi < 4; ++mi)
      #pragma unroll
      for (int ni = 0; ni < 4; ++ni)
        acc[mi][ni] = mfma16(af0[mi], bfr[ni], acc[mi][ni]);
    __builtin_amdgcn_s_setprio(0);
    // ---- phase 1: m-half 1 ----
    bf16x8 af1[4];
    #pragma unroll
    for (int j = 0; j < 4; ++j)
      af1[j] = lds_frag(sA, wr * 128 + 64 + j * 16 + l15, g);
    if (tt + 3 < NT) stageB((tt + 3) & 3);
    asm volatile("s_waitcnt lgkmcnt(0)" ::: "memory");
    if (tt + 1 < NT){
      if (tt + 3 < NT)      asm volatile("s_waitcnt vmcnt(8)" ::: "memory");
      else if (tt + 2 < NT) asm volatile("s_waitcnt vmcnt(4)" ::: "memory");
      else                  asm volatile("s_waitcnt vmcnt(0)" ::: "memory");
    }
    __builtin_amdgcn_s_barrier();
    __builtin_amdgcn_s_setprio(1);
    #pragma unroll
    for (int mi = 0; mi < 4; ++mi)
      #pragma unroll
      for (int ni = 0; ni < 4; ++ni)
        acc[4 + mi][ni] = mfma16(af1[mi], bfr[ni], acc[4 + mi][ni]);
    __builtin_amdgcn_s_setprio(0);
  }
  // ---- epilogue ----
  const int row0 = bm * 256 + wr * 128, col0 = bn * 256 + wc * 64;
  #pragma unroll
  for (int mi = 0; mi < 8; ++mi){
    #pragma unroll
    for (int ni = 0; ni < 4; ++ni){
      #pragma unroll
      for (int r = 0; r < 4; ++r){
        const long ri = row0 + mi * 16 + g * 4 + r;
        const long ci = col0 + ni * 16 + l15;
        const float v = acc[mi][ni][r];
        if (OUT_BF16) ((u16*)C)[ri * N + ci] = f2bf(v);
        else          ((float*)C)[ri * N + ci] = v;
      }
    }
  }
}

// -------------------- RoPE in-place on bf16 qkv --------------------
__global__ void k_rope(u16* __restrict__ qkv){
  const int idx = blockIdx.x * 256 + threadIdx.x;   // S * 20 * 64
  const int i = idx & 63;
  const int head = (idx >> 6) % 20;
  const int s = idx / (64 * 20);
  const long base = (long)s * NQKV + (head < NHQ ? head * HDIM : DMODEL + (head - NHQ) * HDIM);
  u32* p = (u32*)(qkv + base + 2 * i);
  const u32 v = *p;
  const float x0 = bf2f((u16)(v & 0xffffu)), x1 = bf2f((u16)(v >> 16));
  const float ang = (float)s * exp2f(-0.29580575889569023f * (float)i);
  float sn, cs;
  sincosf(ang, &sn, &cs);
  const float y0 = x0 * cs - x1 * sn;
  const float y1 = x0 * sn + x1 * cs;
  *p = (u32)f2bf(y0) | ((u32)f2bf(y1) << 16);
}

// -------------------- Flash attention (causal, GQA), gload_lds staged ------------
// K tile [64 kv][128 d]: row = 16 slots x 16B, slot XOR (row&15).
// V tile (from pre-transposed vT): [128 d][64 kv]: row = 8 slots, XOR (row&7).
// Double-buffered, counted vmcnt(8). 8 gload_lds per thread per tile.
__global__ __launch_bounds__(256) void k_attn(const u16* __restrict__ qkv,
                                              const u16* __restrict__ vT,
                                              u16* __restrict__ o){
  const int qb = blockIdx.x, h = blockIdx.y;
  const int kh = h >> 2;                      // GQA: G=4
  const int t = threadIdx.x, w = t >> 6, lane = t & 63, l15 = lane & 15, g = lane >> 4;
  __shared__ u16 Ks[2][8192];   // 16 KB per buf
  __shared__ u16 Vs[2][8192];
  __shared__ u16 Ps[4][16 * 72];
  const int q0 = qb * 64 + w * 16;
  bf16x8 aq[4];
  #pragma unroll
  for (int d0 = 0; d0 < 4; ++d0)
    aq[d0] = ld8(qkv + (long)(q0 + l15) * NQKV + h * HDIM + d0 * 32 + g * 8);
  f32x4 acc_o[8] = {};
  float mst[4], lst[4];
  #pragma unroll
  for (int r = 0; r < 4; ++r){ mst[r] = -1e30f; lst[r] = 0.f; }
  const float scale = 0.08838834764831843f;

  auto stageK = [&](int kt, int b){
    #pragma unroll
    for (int p = 0; p < 4; ++p){
      const int q = p * 256 + t;
      const int r = q >> 4, u = q & 15;
      const u16* gp = qkv + (long)(kt * 64 + r) * NQKV + DMODEL + kh * HDIM + ((u ^ (r & 15)) << 3);
      GLOAD_LDS16(gp, Ks[b] + (p * 256 + (t & ~63)) * 8);
    }
  };
  auto stageV = [&](int kt, int b){
    #pragma unroll
    for (int p = 0; p < 4; ++p){
      const int q = p * 256 + t;
      const int r = q >> 3, u = q & 7;
      const u16* gp = vT + ((long)kh * HDIM + r) * S_LEN + kt * 64 + ((u ^ (r & 7)) << 3);
      GLOAD_LDS16(gp, Vs[b] + (p * 256 + (t & ~63)) * 8);
    }
  };

  const int nkt = qb + 1;
  stageK(0, 0); stageV(0, 0);
  for (int kt = 0; kt < nkt; ++kt){
    const int kv0 = kt << 6;
    __builtin_amdgcn_s_barrier();            // (a) all prev reads drained -> DMA may overwrite
    if (kt + 1 < nkt){
      stageK(kt + 1, (kt + 1) & 1);
      stageV(kt + 1, (kt + 1) & 1);
      asm volatile("s_waitcnt vmcnt(8)" ::: "memory");
    } else {
      asm volatile("s_waitcnt vmcnt(0)" ::: "memory");
    }
    __builtin_amdgcn_s_barrier();            // (b) tile kt globally visible
    const u16* K_ = Ks[kt & 1];
    const u16* V_ = Vs[kt & 1];
    // ---- S = Q K^T ----
    f32x4 sacc[4] = {};
    #pragma unroll
    for (int d0 = 0; d0 < 4; ++d0){
      #pragma unroll
      for (int j = 0; j < 4; ++j){
        const bf16x8 bk = ld8(K_ + (j * 16 + l15) * 128 + ((((d0 << 2) | g) ^ l15) << 3));
        sacc[j] = mfma16(aq[d0], bk, sacc[j]);
      }
    }
    // ---- mask + online softmax (rows in 16-lane groups) ----
    float p[4][4], scl[4];
    #pragma unroll
    for (int r = 0; r < 4; ++r){
      const int qrow = q0 + g * 4 + r;
      float mx = -1e30f;
      #pragma unroll
      for (int j = 0; j < 4; ++j){
        float sv = sacc[j][r] * scale;
        sv = (kv0 + j * 16 + l15 <= qrow) ? sv : -1e30f;
        p[j][r] = sv;
        mx = fmaxf(mx, sv);
      }
      #pragma unroll
      for (int off = 1; off < 16; off <<= 1) mx = fmaxf(mx, __shfl_xor(mx, off, 64));
      const float mnew = fmaxf(mst[r], mx);
      scl[r] = __expf(mst[r] - mnew);
      float rs = 0.f;
      #pragma unroll
      for (int j = 0; j < 4; ++j){ p[j][r] = __expf(p[j][r] - mnew); rs += p[j][r]; }
      #pragma unroll
      for (int off = 1; off < 16; off <<= 1) rs += __shfl_xor(rs, off, 64);
      lst[r] = lst[r] * scl[r] + rs;
      mst[r] = mnew;
    }
    #pragma unroll
    for (int n = 0; n < 8; ++n)
      #pragma unroll
      for (int r = 0; r < 4; ++r)
        acc_o[n][r] *= scl[r];
    // ---- P -> LDS (per-wave), then PV ----
    #pragma unroll
    for (int j = 0; j < 4; ++j)
      #pragma unroll
      for (int r = 0; r < 4; ++r)
        Ps[w][(g * 4 + r) * 72 + j * 16 + l15] = f2bf(p[j][r]);
    #pragma unroll
    for (int kk = 0; kk < 2; ++kk){
      const bf16x8 pa = ld8(Ps[w] + l15 * 72 + kk * 32 + g * 8);
      #pragma unroll
      for (int n = 0; n < 8; ++n){
        const int row = n * 16 + l15;
        const bf16x8 bv = ld8(V_ + row * 64 + ((((kk << 2) | g) ^ (l15 & 7)) << 3));
        acc_o[n] = mfma16(pa, bv, acc_o[n]);
      }
    }
    asm volatile("s_waitcnt lgkmcnt(0)" ::: "memory");   // drain my LDS reads (WAR)
  }
  #pragma unroll
  for (int n = 0; n < 8; ++n){
    #pragma unroll
    for (int r = 0; r < 4; ++r){
      const float ov = acc_o[n][r] / lst[r];
      o[(long)(q0 + g * 4 + r) * DMODEL + h * HDIM + n * 16 + l15] = f2bf(ov);
    }
  }
}

// -------------------- SwiGLU: silu(gate)*up --------------------
__global__ void k_swiglu(const u16* __restrict__ gu, u16* __restrict__ out){
  const long idx = ((long)blockIdx.x * 256 + threadIdx.x) * 8;
  const long s = idx >> 13;
  const int j = (int)(idx & 8191);
  const u16* gp = gu + s * 16384 + j;
  const uint4 gv = *(const uint4*)gp;
  const uint4 uv = *(const uint4*)(gp + PDIM);
  const u32 gw[4] = {gv.x, gv.y, gv.z, gv.w};
  const u32 uw[4] = {uv.x, uv.y, uv.z, uv.w};
  u32 ow[4];
  #pragma unroll
  for (int k = 0; k < 4; ++k){
    const float g0 = bf2f((u16)(gw[k] & 0xffffu)), g1 = bf2f((u16)(gw[k] >> 16));
    const float u0 = bf2f((u16)(uw[k] & 0xffffu)), u1 = bf2f((u16)(uw[k] >> 16));
    const float s0 = g0 / (1.f + __expf(-g0)) * u0;
    const float s1 = g1 / (1.f + __expf(-g1)) * u1;
    ow[k] = (u32)f2bf(s0) | ((u32)f2bf(s1) << 16);
  }
  uint4 ro; ro.x = ow[0]; ro.y = ow[1]; ro.z = ow[2]; ro.w = ow[3];
  *(uint4*)(out + idx) = ro;
}

// -------------------- launch --------------------
extern "C" void kernel_launch(void* const* d_in, const int* in_sizes, int n_in,
                              void* d_out, int out_size, void* d_ws, size_t ws_size,
                              hipStream_t stream){
  const int*   tokens       = (const int*)d_in[0];
  const float* embed        = (const float*)d_in[1];
  const float* attn_norm_w  = (const float*)d_in[2];
  const float* qkv_w        = (const float*)d_in[3];
  const float* attn_out_w   = (const float*)d_in[4];
  const float* mlp_norm_w   = (const float*)d_in[5];
  const float* mlp_in_w     = (const float*)d_in[6];
  const float* mlp_out_w    = (const float*)d_in[7];
  const float* final_norm_w = (const float*)d_in[8];
  const float* lm_head_w    = (const float*)d_in[9];

  char* ws = (char*)d_ws;
  float* xf  = (float*)(ws);                    // 16.78 MB residual (fp32)
  u16* hbf   = (u16*)(ws + 16777216);           //  8.39 MB normed activations
  u16* qkvb  = (u16*)(ws + 25165824);           // 12.58 MB qkv
  u16* obf   = (u16*)(ws + 37748736);           //  8.39 MB attn out
  u16* gub   = (u16*)(ws + 46137344);           // 67.11 MB gate|up
  u16* hb2   = (u16*)(ws + 113246208);          // 33.55 MB silu(g)*u
  u16* wbuf  = (u16*)(ws + 146800640);          // 131.07 MB transposed bf16 weights
  u16* vTb   = (u16*)(ws + 277872640);          //  2.10 MB transposed V

  k_embed<<<S_LEN, 256, 0, stream>>>(tokens, embed, xf);
  for (int l = 0; l < 2; ++l){
    k_rmsnorm<<<S_LEN, 256, 0, stream>>>(xf, attn_norm_w + (long)l * DMODEL, hbf);
    k_convT<<<dim3(NQKV/64, DMODEL/64), 256, 0, stream>>>(
        qkv_w + (long)l * DMODEL * NQKV, wbuf, NQKV, DMODEL);
    k_gemm<1,0><<<dim3(S_LEN/128, NQKV/128), 256, 0, stream>>>(
        hbf, wbuf, qkvb, nullptr, S_LEN, NQKV, DMODEL);
    k_rope<<<(S_LEN * 20 * 64) / 256, 256, 0, stream>>>(qkvb);
    k_transV<<<dim3(S_LEN/64, 2, 4), 256, 0, stream>>>(qkvb, vTb);
    k_attn<<<dim3(S_LEN/64, NHQ), 256, 0, stream>>>(qkvb, vTb, obf);
    k_convT<<<dim3(DMODEL/64, DMODEL/64), 256, 0, stream>>>(
        attn_out_w + (long)l * DMODEL * DMODEL, wbuf, DMODEL, DMODEL);
    k_gemm<0,1><<<dim3(S_LEN/128, DMODEL/128), 256, 0, stream>>>(
        obf, wbuf, xf, xf, S_LEN, DMODEL, DMODEL);
    k_rmsnorm<<<S_LEN, 256, 0, stream>>>(xf, mlp_norm_w + (long)l * DMODEL, hbf);
    k_convT<<<dim3((2*PDIM)/64, DMODEL/64), 256, 0, stream>>>(
        mlp_in_w + (long)l * DMODEL * 2 * PDIM, wbuf, 2*PDIM, DMODEL);
    k_gemm256<1><<<(S_LEN/256) * ((2*PDIM)/256), 512, 0, stream>>>(
        hbf, wbuf, gub, S_LEN, 2*PDIM, DMODEL);
    k_swiglu<<<(S_LEN * PDIM / 8) / 256, 256, 0, stream>>>(gub, hb2);
    k_convT<<<dim3(DMODEL/64, PDIM/64), 256, 0, stream>>>(
        mlp_out_w + (long)l * PDIM * DMODEL, wbuf, DMODEL, PDIM);
    k_gemm<0,1><<<dim3(S_LEN/128, DMODEL/128), 256, 0, stream>>>(
        hb2, wbuf, xf, xf, S_LEN, DMODEL, PDIM);
  }
  k_rmsnorm<<<S_LEN, 256, 0, stream>>>(xf, final_norm_w, hbf);
  k_convT<<<dim3(VOCAB/64, DMODEL/64), 256, 0, stream>>>(lm_head_w, wbuf, VOCAB, DMODEL);
  k_gemm256<0><<<(S_LEN/256) * (VOCAB/256), 512, 0, stream>>>(
      hbf, wbuf, (float*)d_out, S_LEN, VOCAB, DMODEL);
}